// Round 4
// baseline (361.048 us; speedup 1.0000x reference)
//
#include <hip/hip_runtime.h>
#include <math.h>

#define NB    1024
#define NC    62
#define NBAND 5
#define NOUT  16
#define NHID  10
#define XSTR  68   // Xc row stride (mult of 4 for float4; 68%32=4 keeps conflicts 2-way)

// =====================================================================
// Kernel A: gate-cancelled SPD.
//   relu(softmax(s)*x) = g*relu(x); cov/trace cancels g^2 and 1/(c-1):
//   com[b,k] = 0.5*(N(relu(pcc_t)) + N(relu(A))) + 1e-5*I,
//   N(X) = Xc^T Xc / ||Xc||_F^2, Xc row-centered. conv_w/conv_b dead.
// Load/center: thread (j=tid>>2, q=tid&3) owns row j cols q*16..+15, reg
// centering via 4-lane shuffles. SYRK: remapped to 4x4 register tiles
// (tj=tid>>4, tl=tid&15) -> 32 B LDS per 16 FMA (was 68 B per 16).
// =====================================================================
__global__ __launch_bounds__(256) void k_spd(
    const float* __restrict__ pcc, const float* __restrict__ Aadj,
    const float* __restrict__ hlin_w, const float* __restrict__ elin_w,
    float* __restrict__ com, float* __restrict__ lwT, float* __restrict__ rsumG) {
  const int bk = (blockIdx.x & 7) * 640 + (blockIdx.x >> 3);  // XCD swizzle, 5120%8==0
  const int b = bk / NBAND, k = bk % NBAND;
  __shared__ __align__(16) float Xc[NC * XSTR];
  __shared__ float red4[4];
  const int tid = threadIdx.x;
  const int j = tid >> 2, q = tid & 3, o0 = q * 16;
  const int wave = tid >> 6, lane = tid & 63;
  const bool act = (j < NC);

  float ld[16];

  // ---- src0 = relu(pcc[b,:,:,k]) : row-per-group load
#pragma unroll
  for (int u = 0; u < 16; ++u) ld[u] = 0.f;
  if (act) {
    const float* src = pcc + ((size_t)(b * NC + j) * NC + o0) * NBAND + k;
#pragma unroll
    for (int u = 0; u < 16; ++u)
      if (o0 + u < NC) ld[u] = fmaxf(src[u * NBAND], 0.f);
  }
  float rs = 0.f;
#pragma unroll
  for (int u = 0; u < 16; ++u) rs += ld[u];
  rs += __shfl_xor(rs, 1, 64);
  rs += __shfl_xor(rs, 2, 64);
  const float m0 = rs * (1.f / NC);
  float sq = 0.f;
  if (act) {
#pragma unroll
    for (int u = 0; u < 16; ++u) {
      const float cv = (o0 + u < NC) ? (ld[u] - m0) : 0.f;
      Xc[j * XSTR + o0 + u] = cv;
      sq += cv * cv;
    }
  }
#pragma unroll
  for (int off = 1; off < 64; off <<= 1) sq += __shfl_xor(sq, off, 64);
  if (lane == 0) red4[wave] = sq;

  // prefetch src1 = Aadj[b,k] rows into regs (lands under SYRK0)
#pragma unroll
  for (int u = 0; u < 16; ++u) ld[u] = 0.f;
  if (act) {
    const float* src = Aadj + ((size_t)(b * NBAND + k) * NC + j) * NC + o0;
#pragma unroll
    for (int u = 0; u < 16; ++u)
      if (o0 + u < NC) ld[u] = src[u];
  }
  __syncthreads();   // (1) Xc0 + red4 ready

  // ---- SYRK0 with 4x4 tiles: G[j0+jj][l0+e], j0=4*tj, l0=4*tl
  const int tj = tid >> 4, tl = tid & 15;
  float acc0[16];
#pragma unroll
  for (int u = 0; u < 16; ++u) acc0[u] = 0.f;
  for (int i = 0; i < NC; ++i) {
    float wj[4], wl[4];
    *reinterpret_cast<float4*>(wj) = *reinterpret_cast<const float4*>(&Xc[i * XSTR + 4 * tj]);
    *reinterpret_cast<float4*>(wl) = *reinterpret_cast<const float4*>(&Xc[i * XSTR + 4 * tl]);
#pragma unroll
    for (int jj = 0; jj < 4; ++jj)
#pragma unroll
      for (int e = 0; e < 4; ++e) acc0[jj * 4 + e] += wj[jj] * wl[e];
  }
  const float tra0 = red4[0] + red4[1] + red4[2] + red4[3];  // read BEFORE barrier (2)
  __syncthreads();   // (2) SYRK0 reads done; Xc/red4 reusable

  // ---- src1: relu + center in regs, write Xc
#pragma unroll
  for (int u = 0; u < 16; ++u) ld[u] = fmaxf(ld[u], 0.f);
  rs = 0.f;
#pragma unroll
  for (int u = 0; u < 16; ++u) rs += ld[u];
  rs += __shfl_xor(rs, 1, 64);
  rs += __shfl_xor(rs, 2, 64);
  const float m1 = rs * (1.f / NC);
  sq = 0.f;
  if (act) {
#pragma unroll
    for (int u = 0; u < 16; ++u) {
      const float cv = (o0 + u < NC) ? (ld[u] - m1) : 0.f;
      Xc[j * XSTR + o0 + u] = cv;
      sq += cv * cv;
    }
  }
#pragma unroll
  for (int off = 1; off < 64; off <<= 1) sq += __shfl_xor(sq, off, 64);
  if (lane == 0) red4[wave] = sq;
  __syncthreads();   // (3) Xc1 + red4 ready

  float acc1[16];
#pragma unroll
  for (int u = 0; u < 16; ++u) acc1[u] = 0.f;
  for (int i = 0; i < NC; ++i) {
    float wj[4], wl[4];
    *reinterpret_cast<float4*>(wj) = *reinterpret_cast<const float4*>(&Xc[i * XSTR + 4 * tj]);
    *reinterpret_cast<float4*>(wl) = *reinterpret_cast<const float4*>(&Xc[i * XSTR + 4 * tl]);
#pragma unroll
    for (int jj = 0; jj < 4; ++jj)
#pragma unroll
      for (int e = 0; e < 4; ++e) acc1[jj * 4 + e] += wj[jj] * wl[e];
  }
  const float tra1 = red4[0] + red4[1] + red4[2] + red4[3];

  // ---- combine + store (float2: rows are 62 floats -> only 8B-aligned)
  {
    const float s0 = 0.5f / tra0, s1 = 0.5f / tra1;
#pragma unroll
    for (int jj = 0; jj < 4; ++jj) {
      const int r = 4 * tj + jj;
      if (r < NC) {
        float v[4];
#pragma unroll
        for (int e = 0; e < 4; ++e) {
          v[e] = acc0[jj * 4 + e] * s0 + acc1[jj * 4 + e] * s1;
          if (tj == tl && jj == e) v[e] += 1e-5f;
        }
        float* rowp = com + (size_t)bk * (NC * NC) + r * NC + 4 * tl;
        if (tl < 15) {
          *reinterpret_cast<float2*>(rowp) = make_float2(v[0], v[1]);
          *reinterpret_cast<float2*>(rowp + 2) = make_float2(v[2], v[3]);
        } else {  // cols 60..63 -> only 60,61 valid
          *reinterpret_cast<float2*>(rowp) = make_float2(v[0], v[1]);
        }
      }
    }
  }

  // ---- block 0 epilogue: zero-padded lw transposes [c][o] + row sums
  if (blockIdx.x == 0) {
    for (int t = tid; t < NC * 64; t += 256) {
      const int c = t >> 6, o = t & 63;
      lwT[t]           = (o < NC) ? hlin_w[o * NC + c] : 0.f;
      lwT[NC * 64 + t] = (o < NC) ? elin_w[o * NC + c] : 0.f;
    }
    if (tid < 64) {
      float sh = 0.f, se = 0.f;
      if (tid < NC) {
        for (int c = 0; c < NC; ++c) { sh += hlin_w[tid * NC + c]; se += elin_w[tid * NC + c]; }
      }
      rsumG[tid] = sh;
      rsumG[64 + tid] = se;
    }
  }
}

// =====================================================================
// Kernel B (v3): one 64-thread wave per (b,br); online softmax over bands.
// Thread (rq=lane>>2, q=lane&3) owns z rows {rq,rq+16,rq+32,rq+48} x cols
// q*16..+15 -> per c-step: 4 com scalars + 4 float4 lwT = 80 B per 64 FMA.
// com is SYMMETRIC, so comS[c][j] = com[j][c] needs no transpose.
// Next band's comS is async-staged: global->regs at GEMM start,
// ds_write right after GEMM (T14). Single wave -> no barriers.
// =====================================================================
__global__ __launch_bounds__(64) void k_branch(
    const float* __restrict__ com, const float* __restrict__ lwT,
    const float* __restrict__ rsumG,
    const float* __restrict__ hconv_w, const float* __restrict__ hconv_b,
    const float* __restrict__ hlin_b,
    const float* __restrict__ econv_w, const float* __restrict__ econv_b,
    const float* __restrict__ elin_b,
    const float* __restrict__ att_w1,  const float* __restrict__ att_b1,
    const float* __restrict__ att_w2,
    float* __restrict__ hiddenO, float* __restrict__ essentialO) {
  const int bid = (blockIdx.x & 7) * 256 + (blockIdx.x >> 3);  // XCD swizzle; br-pair co-XCD
  const int b = bid >> 1, br = bid & 1;

  const float* __restrict__ cw = br ? econv_w : hconv_w;
  const float* __restrict__ cb = br ? econv_b : hconv_b;
  const float* __restrict__ lb = br ? elin_b : hlin_b;
  float* __restrict__ outp = br ? essentialO : hiddenO;

  __shared__ __align__(16) float comS[64 * NC];   // rows 0..61 = com band, 62/63 zeroed
  __shared__ __align__(16) float lwTS[NC * 64];   // [c][o], zero-padded o>=62
  __shared__ float w1S[NHID * 64];                // [h][o], zero-padded
  __shared__ float rsumS[64], lbS[64];

  const int lane = threadIdx.x;
  const int rq = lane >> 2, q = lane & 3, o0 = q * 16;

  // uniform params -> (scalar) regs
  float b1R[NHID], w2R[NHID], cwR[NBAND], cbR[NBAND];
#pragma unroll
  for (int h = 0; h < NHID; ++h) { b1R[h] = att_b1[h]; w2R[h] = att_w2[h]; }
#pragma unroll
  for (int kk = 0; kk < NBAND; ++kk) { cwR[kk] = cw[kk]; cbR[kk] = cb[kk]; }

  // LDS fills (single wave: DS in-order, no barriers needed)
  {
    const float4* src = reinterpret_cast<const float4*>(lwT + br * (NC * 64));
    float4* dst = reinterpret_cast<float4*>(lwTS);
#pragma unroll
    for (int i = 0; i < 16; ++i) {
      const int idx = lane + i * 64;
      if (idx < NC * 16) dst[idx] = src[idx];   // 992 float4s
    }
  }
  for (int t = lane; t < NHID * 64; t += 64) {
    const int c = t & 63;
    w1S[t] = (c < NC) ? att_w1[(t >> 6) * NC + c] : 0.f;
  }
  rsumS[lane] = rsumG[br * 64 + lane];
  lbS[lane] = (lane < NC) ? lb[lane] : 0.f;
  // zero comS rows 62,63 (never written by band fills; keep everything finite)
  comS[62 * NC + lane] = 0.f;
  comS[62 * NC + 64 + lane] = 0.f;
  if (lane < 124 - 128 + 64) {}  // no-op
  comS[62 * NC + 2 * 64 > 64 * NC - 1 ? 0 : 62 * NC] = comS[62 * NC];  // keep simple; extra zeros below
  for (int t = 62 * NC + lane; t < 64 * NC; t += 64) comS[t] = 0.f;

  // band 0 comS fill (961 float4s = 3844 floats)
  {
    const float4* src = reinterpret_cast<const float4*>(com + (size_t)(b * NBAND) * (NC * NC));
    float4* dst = reinterpret_cast<float4*>(comS);
#pragma unroll
    for (int i = 0; i < 15; ++i) dst[lane + i * 64] = src[lane + i * 64];
    if (lane == 0) dst[960] = src[960];
  }

  float oacc[4][16];
#pragma unroll
  for (int s = 0; s < 4; ++s)
#pragma unroll
    for (int u = 0; u < 16; ++u) oacc[s][u] = 0.f;
  float denom[4] = {0.f, 0.f, 0.f, 0.f};
  float mrun[4] = {-1e30f, -1e30f, -1e30f, -1e30f};

  for (int kb = 0; kb < NBAND; ++kb) {
    // T14: issue next band's global loads now; write to LDS after the GEMM
    float4 pf[15]; float4 pft;
    if (kb < NBAND - 1) {
      const float4* src = reinterpret_cast<const float4*>(com + (size_t)(b * NBAND + kb + 1) * (NC * NC));
#pragma unroll
      for (int i = 0; i < 15; ++i) pf[i] = src[lane + i * 64];
      if (lane == 0) pft = src[960];
    }

    // GEMM: accz[s][u] = sum_c com[r_s][c] * lw[o0+u][c]  (com symmetric)
    float accz[4][16];
#pragma unroll
    for (int s = 0; s < 4; ++s)
#pragma unroll
      for (int u = 0; u < 16; ++u) accz[s][u] = 0.f;
#pragma unroll 2
    for (int c = 0; c < NC; ++c) {
      const float a0 = comS[rq * NC + c];
      const float a1 = comS[(rq + 16) * NC + c];
      const float a2 = comS[(rq + 32) * NC + c];
      const float a3 = comS[(rq + 48) * NC + c];
      float wv[16];
      *reinterpret_cast<float4*>(&wv[0])  = *reinterpret_cast<const float4*>(&lwTS[c * 64 + o0 + 0]);
      *reinterpret_cast<float4*>(&wv[4])  = *reinterpret_cast<const float4*>(&lwTS[c * 64 + o0 + 4]);
      *reinterpret_cast<float4*>(&wv[8])  = *reinterpret_cast<const float4*>(&lwTS[c * 64 + o0 + 8]);
      *reinterpret_cast<float4*>(&wv[12]) = *reinterpret_cast<const float4*>(&lwTS[c * 64 + o0 + 12]);
#pragma unroll
      for (int u = 0; u < 16; ++u) {
        accz[0][u] += a0 * wv[u];
        accz[1][u] += a1 * wv[u];
        accz[2][u] += a2 * wv[u];
        accz[3][u] += a3 * wv[u];
      }
    }

    // stage next band into comS (WAR-safe: same-wave DS ops are in order)
    if (kb < NBAND - 1) {
      float4* dst = reinterpret_cast<float4*>(comS);
#pragma unroll
      for (int i = 0; i < 15; ++i) dst[lane + i * 64] = pf[i];
      if (lane == 0) dst[960] = pft;
    }

    // sigmoid in place -> z
    const float ck = cwR[kb], dk = cbR[kb];
#pragma unroll
    for (int s = 0; s < 4; ++s)
#pragma unroll
      for (int u = 0; u < 16; ++u) {
        const float zv = ck * accz[s][u] + dk * rsumS[o0 + u] + lbS[o0 + u];
        accz[s][u] = 1.f / (1.f + __expf(-zv));
      }

    // scorer: per h, per-row partials over own 16 cols, 4-lane xor reduce,
    // lane q finishes row rq+16*q; tanh via exp2-free fast form
    float sacc = 0.f;
#pragma unroll
    for (int h = 0; h < NHID; ++h) {
      float p0 = 0.f, p1 = 0.f, p2 = 0.f, p3 = 0.f;
#pragma unroll
      for (int u = 0; u < 16; ++u) {
        const float wh = w1S[h * 64 + o0 + u];
        p0 += accz[0][u] * wh;
        p1 += accz[1][u] * wh;
        p2 += accz[2][u] * wh;
        p3 += accz[3][u] * wh;
      }
      p0 += __shfl_xor(p0, 1, 64); p0 += __shfl_xor(p0, 2, 64);
      p1 += __shfl_xor(p1, 1, 64); p1 += __shfl_xor(p1, 2, 64);
      p2 += __shfl_xor(p2, 1, 64); p2 += __shfl_xor(p2, 2, 64);
      p3 += __shfl_xor(p3, 1, 64); p3 += __shfl_xor(p3, 2, 64);
      const float Ysel = (q == 0) ? p0 : (q == 1) ? p1 : (q == 2) ? p2 : p3;
      const float ex = __expf(2.f * (Ysel + b1R[h]));
      sacc += w2R[h] * (1.f - 2.f / (ex + 1.f));   // tanh
    }
    // broadcast the 4 row scores within the 4-lane group
    const int gbase = lane & 60;
    float sc[4];
#pragma unroll
    for (int s = 0; s < 4; ++s) sc[s] = __shfl(sacc, gbase + s, 64);

    // online softmax accumulate (per row)
#pragma unroll
    for (int s = 0; s < 4; ++s) {
      const float nm = fmaxf(mrun[s], sc[s]);
      const float f = __expf(mrun[s] - nm), e = __expf(sc[s] - nm);
      denom[s] = denom[s] * f + e;
#pragma unroll
      for (int u = 0; u < 16; ++u) oacc[s][u] = oacc[s][u] * f + e * accz[s][u];
      mrun[s] = nm;
    }
  }

  // store (float2: row base 62 floats -> 8B aligned)
#pragma unroll
  for (int s = 0; s < 4; ++s) {
    const int r = rq + 16 * s;
    if (r < NC) {
      const float inv = 1.f / denom[s];
      float* rowp = outp + (size_t)b * (NC * NC) + r * NC + o0;
      if (q < 3) {
#pragma unroll
        for (int e = 0; e < 8; ++e)
          *reinterpret_cast<float2*>(rowp + 2 * e) =
              make_float2(oacc[s][2 * e] * inv, oacc[s][2 * e + 1] * inv);
      } else {  // cols 48..61
#pragma unroll
        for (int e = 0; e < 7; ++e)
          *reinterpret_cast<float2*>(rowp + 2 * e) =
              make_float2(oacc[s][2 * e] * inv, oacc[s][2 * e + 1] * inv);
      }
    }
  }
}

// =====================================================================
// Kernel C: Chebyshev GCN (both adjacencies, shared de@gc_w), feature,
// and the 992->62 FC. wnorm == 1 exactly; relu((h+e)/2) no-op on relu'd h,e.
// =====================================================================
__global__ __launch_bounds__(256) void k_cheb_fc(
    const float* __restrict__ de, const float* __restrict__ hidden,
    const float* __restrict__ essential, const float* __restrict__ gc_w,
    const float* __restrict__ gc_b, const float* __restrict__ fc_w,
    const float* __restrict__ fc_b, float* __restrict__ zmat) {
  const int b = blockIdx.x;
  __shared__ float hidS[NC * NC], essS[NC * NC];
  __shared__ float t0S[NC * NOUT], t1S[NC * NOUT];
  __shared__ float featS[NC * NOUT];
  __shared__ float deS[NC * NBAND];
  __shared__ float red2[256];
  const int tid = threadIdx.x;

  for (int t = tid; t < NC * NBAND; t += 256) deS[t] = de[b * NC * NBAND + t];
  for (int t = tid; t < NC * NC; t += 256) {
    hidS[t] = hidden[b * NC * NC + t];
    essS[t] = essential[b * NC * NC + t];
  }
  __syncthreads();
  for (int t = tid; t < NC * NOUT; t += 256) {
    const int i = t / NOUT, f = t % NOUT;
    float a0 = gc_b[f];
    float a1 = 0.f;
#pragma unroll
    for (int qq = 0; qq < NBAND; ++qq) {
      const float d = deS[i * NBAND + qq];
      a0 += d * gc_w[qq * NOUT + f];
      a1 += d * gc_w[(NBAND + qq) * NOUT + f];
    }
    t0S[t] = a0;
    t1S[t] = a1;
  }
  __syncthreads();
  for (int t = tid; t < NC * NOUT; t += 256) {
    const int i = t / NOUT, f = t % NOUT;
    float sh = 0.f, se = 0.f;
    for (int jj = 0; jj < NC; ++jj) {
      const float t1 = t1S[jj * NOUT + f];
      sh += hidS[i * NC + jj] * t1;
      se += essS[i * NC + jj] * t1;
    }
    const float gb1 = gc_b[NOUT + f];
    const float h = fmaxf(t0S[t] + sh + gb1, 0.f);
    const float e = fmaxf(t0S[t] + se + gb1, 0.f);
    featS[t] = 0.5f * (h + e);
  }
  __syncthreads();
  {
    const int n = tid >> 2, qq = tid & 3;
    float p = 0.f;
    if (n < NC) {
      const float* fw = fc_w + n * (NC * NOUT) + qq * 248;
      const float* fs = featS + qq * 248;
      for (int m = 0; m < 248; ++m) p += fs[m] * fw[m];
    }
    red2[tid] = p;
    __syncthreads();
    if (tid < NC) {
      const float z = red2[tid * 4] + red2[tid * 4 + 1] + red2[tid * 4 + 2] + red2[tid * 4 + 3] + fc_b[tid];
      zmat[b * NC + tid] = z;
    }
  }
}

// =====================================================================
// Kernel D1: batch-norm statistics (training-mode batch stats, ddof=0).
// =====================================================================
__global__ __launch_bounds__(256) void k_bnstats(
    const float* __restrict__ zmat, const float* __restrict__ bn_g,
    const float* __restrict__ bn_b, float* __restrict__ bnp) {
  const int n = blockIdx.x;
  __shared__ float rs[256], rq[256];
  const int tid = threadIdx.x;
  float s = 0.f, sq = 0.f;
  for (int r = tid; r < NB; r += 256) {
    const float v = zmat[r * NC + n];
    s += v;
    sq += v * v;
  }
  rs[tid] = s; rq[tid] = sq;
  __syncthreads();
  for (int st = 128; st > 0; st >>= 1) {
    if (tid < st) { rs[tid] += rs[tid + st]; rq[tid] += rq[tid + st]; }
    __syncthreads();
  }
  if (tid == 0) {
    const float mean = rs[0] * (1.f / NB);
    const float var = rq[0] * (1.f / NB) - mean * mean;
    const float sc = bn_g[n] * rsqrtf(var + 1e-5f);
    bnp[2 * n] = sc;
    bnp[2 * n + 1] = bn_b[n] - mean * sc;
  }
}

// =====================================================================
// Kernel D2: apply BN + sigmoid -> output1; 62->2 FC -> output.
// =====================================================================
__global__ __launch_bounds__(64) void k_bn_out(
    const float* __restrict__ zmat, const float* __restrict__ bnp,
    const float* __restrict__ fc4_w, const float* __restrict__ fc4_b,
    float* __restrict__ out) {
  const int b = blockIdx.x;
  const int lane = threadIdx.x;
  float o1 = 0.f;
  if (lane < NC) {
    float z = zmat[b * NC + lane];
    z = z * bnp[2 * lane] + bnp[2 * lane + 1];
    o1 = 1.f / (1.f + __expf(-z));
    out[b * NC + lane] = o1;
  }
  float p0 = (lane < NC) ? o1 * fc4_w[lane] : 0.f;
  float p1 = (lane < NC) ? o1 * fc4_w[NC + lane] : 0.f;
#pragma unroll
  for (int off = 32; off > 0; off >>= 1) {
    p0 += __shfl_down(p0, off, 64);
    p1 += __shfl_down(p1, off, 64);
  }
  if (lane == 0) {
    out[NB * NC + b * 2 + 0] = p0 + fc4_b[0];
    out[NB * NC + b * 2 + 1] = p1 + fc4_b[1];
  }
}

extern "C" void kernel_launch(void* const* d_in, const int* in_sizes, int n_in,
                              void* d_out, int out_size, void* d_ws, size_t ws_size,
                              hipStream_t stream) {
  const float* de      = (const float*)d_in[0];
  const float* pcc     = (const float*)d_in[1];
  const float* Aadj    = (const float*)d_in[2];
  // d_in[3] conv_w, d_in[4] conv_b: dead (gate cancels in trace-normalized SPD)
  const float* hconv_w = (const float*)d_in[5];
  const float* hconv_b = (const float*)d_in[6];
  const float* hlin_w  = (const float*)d_in[7];
  const float* hlin_b  = (const float*)d_in[8];
  const float* econv_w = (const float*)d_in[9];
  const float* econv_b = (const float*)d_in[10];
  const float* elin_w  = (const float*)d_in[11];
  const float* elin_b  = (const float*)d_in[12];
  const float* att_w1  = (const float*)d_in[13];
  const float* att_b1  = (const float*)d_in[14];
  const float* att_w2  = (const float*)d_in[15];
  const float* gc_w    = (const float*)d_in[16];
  const float* gc_b    = (const float*)d_in[17];
  // d_in[18] wpar: wnorm = exp(w)/exp(w) = 1 exactly for 1-element wpar
  const float* fc_w    = (const float*)d_in[19];
  const float* fc_b    = (const float*)d_in[20];
  const float* bn_g    = (const float*)d_in[21];
  const float* bn_b    = (const float*)d_in[22];
  const float* fc4_w   = (const float*)d_in[23];
  const float* fc4_b   = (const float*)d_in[24];

  float* ws        = (float*)d_ws;
  float* com       = ws;                                 // 19,681,280
  float* hidden    = com + (size_t)NB * NBAND * NC * NC; //  3,936,256
  float* essential = hidden + (size_t)NB * NC * NC;      //  3,936,256
  float* zmat      = essential + (size_t)NB * NC * NC;   //     63,488
  float* bnp       = zmat + (size_t)NB * NC;             //        128
  float* lwT       = bnp + 128;                          //      7,936 (2 x 62 x 64, zero-padded)
  float* rsumG     = lwT + 2 * NC * 64;                  //        128
  // total ~111 MB of workspace

  k_spd<<<NB * NBAND, 256, 0, stream>>>(pcc, Aadj, hlin_w, elin_w, com, lwT, rsumG);
  k_branch<<<NB * 2, 64, 0, stream>>>(com, lwT, rsumG,
      hconv_w, hconv_b, hlin_b,
      econv_w, econv_b, elin_b,
      att_w1, att_b1, att_w2, hidden, essential);
  k_cheb_fc<<<NB, 256, 0, stream>>>(de, hidden, essential, gc_w, gc_b, fc_w, fc_b, zmat);
  k_bnstats<<<NC, 256, 0, stream>>>(zmat, bn_g, bn_b, bnp);
  k_bn_out<<<NB, 64, 0, stream>>>(zmat, bnp, fc4_w, fc4_b, (float*)d_out);
}

// Round 5
// 355.884 us; speedup vs baseline: 1.0145x; 1.0145x over previous
//
#include <hip/hip_runtime.h>
#include <math.h>

#define NB    1024
#define NC    62
#define NBAND 5
#define NOUT  16
#define NHID  10
#define XSTR  68   // Xc row stride (mult of 4 for float4; 68%32=4 keeps conflicts 2-way)

// =====================================================================
// Kernel A: gate-cancelled SPD.
//   relu(softmax(s)*x) = g*relu(x); cov/trace cancels g^2 and 1/(c-1):
//   com[b,k] = 0.5*(N(relu(pcc_t)) + N(relu(A))) + 1e-5*I,
//   N(X) = Xc^T Xc / ||Xc||_F^2, Xc row-centered. conv_w/conv_b dead.
// =====================================================================
__global__ __launch_bounds__(256) void k_spd(
    const float* __restrict__ pcc, const float* __restrict__ Aadj,
    const float* __restrict__ hlin_w, const float* __restrict__ elin_w,
    float* __restrict__ com, float* __restrict__ lwT, float* __restrict__ rsumG) {
  const int bk = (blockIdx.x & 7) * 640 + (blockIdx.x >> 3);  // XCD swizzle, 5120%8==0
  const int b = bk / NBAND, k = bk % NBAND;
  __shared__ __align__(16) float Xc[NC * XSTR];
  __shared__ float red4[4];
  const int tid = threadIdx.x;
  const int j = tid >> 2, q = tid & 3, o0 = q * 16;
  const int wave = tid >> 6, lane = tid & 63;
  const bool act = (j < NC);

  float ld[16];

  // ---- src0 = relu(pcc[b,:,:,k]) : row-per-group load
#pragma unroll
  for (int u = 0; u < 16; ++u) ld[u] = 0.f;
  if (act) {
    const float* src = pcc + ((size_t)(b * NC + j) * NC + o0) * NBAND + k;
#pragma unroll
    for (int u = 0; u < 16; ++u)
      if (o0 + u < NC) ld[u] = fmaxf(src[u * NBAND], 0.f);
  }
  float rs = 0.f;
#pragma unroll
  for (int u = 0; u < 16; ++u) rs += ld[u];
  rs += __shfl_xor(rs, 1, 64);
  rs += __shfl_xor(rs, 2, 64);
  const float m0 = rs * (1.f / NC);
  float sq = 0.f;
  if (act) {
#pragma unroll
    for (int u = 0; u < 16; ++u) {
      const float cv = (o0 + u < NC) ? (ld[u] - m0) : 0.f;
      Xc[j * XSTR + o0 + u] = cv;
      sq += cv * cv;
    }
  }
#pragma unroll
  for (int off = 1; off < 64; off <<= 1) sq += __shfl_xor(sq, off, 64);
  if (lane == 0) red4[wave] = sq;

  // prefetch src1 = Aadj[b,k] rows into regs (lands under SYRK0)
#pragma unroll
  for (int u = 0; u < 16; ++u) ld[u] = 0.f;
  if (act) {
    const float* src = Aadj + ((size_t)(b * NBAND + k) * NC + j) * NC + o0;
#pragma unroll
    for (int u = 0; u < 16; ++u)
      if (o0 + u < NC) ld[u] = src[u];
  }
  __syncthreads();   // (1) Xc0 + red4 ready

  // ---- SYRK0 with 4x4 tiles: G[4*tj+jj][4*tl+e]
  const int tj = tid >> 4, tl = tid & 15;
  float acc0[16];
#pragma unroll
  for (int u = 0; u < 16; ++u) acc0[u] = 0.f;
  for (int i = 0; i < NC; ++i) {
    float wj[4], wl[4];
    *reinterpret_cast<float4*>(wj) = *reinterpret_cast<const float4*>(&Xc[i * XSTR + 4 * tj]);
    *reinterpret_cast<float4*>(wl) = *reinterpret_cast<const float4*>(&Xc[i * XSTR + 4 * tl]);
#pragma unroll
    for (int jj = 0; jj < 4; ++jj)
#pragma unroll
      for (int e = 0; e < 4; ++e) acc0[jj * 4 + e] += wj[jj] * wl[e];
  }
  const float tra0 = red4[0] + red4[1] + red4[2] + red4[3];  // read BEFORE barrier (2)
  __syncthreads();   // (2) SYRK0 reads done; Xc/red4 reusable

  // ---- src1: relu + center in regs, write Xc
#pragma unroll
  for (int u = 0; u < 16; ++u) ld[u] = fmaxf(ld[u], 0.f);
  rs = 0.f;
#pragma unroll
  for (int u = 0; u < 16; ++u) rs += ld[u];
  rs += __shfl_xor(rs, 1, 64);
  rs += __shfl_xor(rs, 2, 64);
  const float m1 = rs * (1.f / NC);
  sq = 0.f;
  if (act) {
#pragma unroll
    for (int u = 0; u < 16; ++u) {
      const float cv = (o0 + u < NC) ? (ld[u] - m1) : 0.f;
      Xc[j * XSTR + o0 + u] = cv;
      sq += cv * cv;
    }
  }
#pragma unroll
  for (int off = 1; off < 64; off <<= 1) sq += __shfl_xor(sq, off, 64);
  if (lane == 0) red4[wave] = sq;
  __syncthreads();   // (3) Xc1 + red4 ready

  float acc1[16];
#pragma unroll
  for (int u = 0; u < 16; ++u) acc1[u] = 0.f;
  for (int i = 0; i < NC; ++i) {
    float wj[4], wl[4];
    *reinterpret_cast<float4*>(wj) = *reinterpret_cast<const float4*>(&Xc[i * XSTR + 4 * tj]);
    *reinterpret_cast<float4*>(wl) = *reinterpret_cast<const float4*>(&Xc[i * XSTR + 4 * tl]);
#pragma unroll
    for (int jj = 0; jj < 4; ++jj)
#pragma unroll
      for (int e = 0; e < 4; ++e) acc1[jj * 4 + e] += wj[jj] * wl[e];
  }
  const float tra1 = red4[0] + red4[1] + red4[2] + red4[3];

  // ---- combine + store (float2: rows are 62 floats -> only 8B-aligned)
  {
    const float s0 = 0.5f / tra0, s1 = 0.5f / tra1;
#pragma unroll
    for (int jj = 0; jj < 4; ++jj) {
      const int r = 4 * tj + jj;
      if (r < NC) {
        float v[4];
#pragma unroll
        for (int e = 0; e < 4; ++e) {
          v[e] = acc0[jj * 4 + e] * s0 + acc1[jj * 4 + e] * s1;
          if (tj == tl && jj == e) v[e] += 1e-5f;
        }
        float* rowp = com + (size_t)bk * (NC * NC) + r * NC + 4 * tl;
        if (tl < 15) {
          *reinterpret_cast<float2*>(rowp) = make_float2(v[0], v[1]);
          *reinterpret_cast<float2*>(rowp + 2) = make_float2(v[2], v[3]);
        } else {  // cols 60..63 -> only 60,61 valid
          *reinterpret_cast<float2*>(rowp) = make_float2(v[0], v[1]);
        }
      }
    }
  }

  // ---- block 0 epilogue: zero-padded lw transposes [c][o] + row sums
  if (blockIdx.x == 0) {
    for (int t = tid; t < NC * 64; t += 256) {
      const int c = t >> 6, o = t & 63;
      lwT[t]           = (o < NC) ? hlin_w[o * NC + c] : 0.f;
      lwT[NC * 64 + t] = (o < NC) ? elin_w[o * NC + c] : 0.f;
    }
    if (tid < 64) {
      float sh = 0.f, se = 0.f;
      if (tid < NC) {
        for (int c = 0; c < NC; ++c) { sh += hlin_w[tid * NC + c]; se += elin_w[tid * NC + c]; }
      }
      rsumG[tid] = sh;
      rsumG[64 + tid] = se;
    }
  }
}

// ---------------------------------------------------------------------
// global->LDS DMA: 16 x width-16 loads stage 4096 floats (overreads past
// the 3844-float band; extra lands in never-read LDS rows 62/63).
// ---------------------------------------------------------------------
__device__ __forceinline__ void stage_com(float* lbuf, const float* src, int lane) {
#pragma unroll
  for (int it = 0; it < 16; ++it) {
    __builtin_amdgcn_global_load_lds(
        (const __attribute__((address_space(1))) void*)(src + (size_t)(it * 64 + lane) * 4),
        (__attribute__((address_space(3))) void*)(lbuf + it * 256),
        16, 0, 0);
  }
}

// =====================================================================
// Kernel B (v5): one 64-thread wave per (b,br); online softmax over bands.
// 4x16 register tile (thread (rq,q) owns rows {rq,+16,+32,+48} x cols
// q*16..+15): 80 B LDS per 64 FMA. com staged via global_load_lds into a
// DOUBLE BUFFER with counted vmcnt (zero VGPR staging cost -> no spill).
// All small params in LDS so the loop body has NO compiler VMEM ops
// (keeps the manual vmcnt counting exact). Band loop fully unrolled.
// =====================================================================
__global__ __launch_bounds__(64, 1) void k_branch(
    const float* __restrict__ com, const float* __restrict__ lwT,
    const float* __restrict__ rsumG,
    const float* __restrict__ hconv_w, const float* __restrict__ hconv_b,
    const float* __restrict__ hlin_b,
    const float* __restrict__ econv_w, const float* __restrict__ econv_b,
    const float* __restrict__ elin_b,
    const float* __restrict__ att_w1,  const float* __restrict__ att_b1,
    const float* __restrict__ att_w2,
    float* __restrict__ hiddenO, float* __restrict__ essentialO) {
  const int bid = (blockIdx.x & 7) * 256 + (blockIdx.x >> 3);  // XCD swizzle
  const int b = bid >> 1, br = bid & 1;

  const float* __restrict__ cw = br ? econv_w : hconv_w;
  const float* __restrict__ cb = br ? econv_b : hconv_b;
  const float* __restrict__ lb = br ? elin_b : hlin_b;
  float* __restrict__ outp = br ? essentialO : hiddenO;

  __shared__ __align__(16) float comS[2][4096];   // 32 KB double buffer
  __shared__ __align__(16) float lwTS[NC * 64];   // [c][o], zero-padded o>=62
  __shared__ float w1S[NHID * 64];                // [h][o], zero-padded
  __shared__ float rsumS[64], lbS[64];
  __shared__ float b1S[16], w2S[16], cwS[8], cbS[8];

  const int lane = threadIdx.x;
  const int rq = lane >> 2, q = lane & 3, o0 = q * 16;

  // ---- LDS fills (single wave: DS ops in-order; no barriers)
  {
    const float4* src = reinterpret_cast<const float4*>(lwT + br * (NC * 64));
    float4* dst = reinterpret_cast<float4*>(lwTS);
#pragma unroll
    for (int i = 0; i < 16; ++i) {
      const int idx = lane + i * 64;
      if (idx < NC * 16) dst[idx] = src[idx];   // 992 float4s
    }
  }
  for (int t = lane; t < NHID * 64; t += 64) {
    const int c = t & 63;
    w1S[t] = (c < NC) ? att_w1[(t >> 6) * NC + c] : 0.f;
  }
  rsumS[lane] = rsumG[br * 64 + lane];
  lbS[lane] = (lane < NC) ? lb[lane] : 0.f;
  if (lane < NHID) { b1S[lane] = att_b1[lane]; w2S[lane] = att_w2[lane]; }
  if (lane < NBAND) { cwS[lane] = cw[lane]; cbS[lane] = cb[lane]; }

  const float* cbase = com + (size_t)(b * NBAND) * (NC * NC);

  // drain all pre-loop VMEM so vmcnt counting below is exact
  asm volatile("s_waitcnt vmcnt(0)" ::: "memory");
  stage_com(comS[0], cbase, lane);                 // band 0
  stage_com(comS[1], cbase + NC * NC, lane);       // band 1

  float oacc[4][16];
#pragma unroll
  for (int s = 0; s < 4; ++s)
#pragma unroll
    for (int u = 0; u < 16; ++u) oacc[s][u] = 0.f;
  float denom[4] = {0.f, 0.f, 0.f, 0.f};
  float mrun[4] = {-1e30f, -1e30f, -1e30f, -1e30f};

#pragma unroll
  for (int kb = 0; kb < NBAND; ++kb) {
    float* cbuf = comS[kb & 1];
    // wait for band kb's 16 loads; band kb+1's 16 stay in flight
    if (kb < NBAND - 1) {
      asm volatile("s_waitcnt vmcnt(16)" ::: "memory");
    } else {
      asm volatile("s_waitcnt vmcnt(0)" ::: "memory");
    }
    __builtin_amdgcn_sched_barrier(0);

    // GEMM: accz[s][u] = sum_c com[r_s][c] * lw[o0+u][c]  (com symmetric)
    float accz[4][16];
#pragma unroll
    for (int s = 0; s < 4; ++s)
#pragma unroll
      for (int u = 0; u < 16; ++u) accz[s][u] = 0.f;
#pragma unroll 2
    for (int c = 0; c < NC; ++c) {
      const float a0 = cbuf[rq * NC + c];
      const float a1 = cbuf[(rq + 16) * NC + c];
      const float a2 = cbuf[(rq + 32) * NC + c];
      const float a3 = cbuf[(rq + 48) * NC + c];
      float wv[16];
      *reinterpret_cast<float4*>(&wv[0])  = *reinterpret_cast<const float4*>(&lwTS[c * 64 + o0 + 0]);
      *reinterpret_cast<float4*>(&wv[4])  = *reinterpret_cast<const float4*>(&lwTS[c * 64 + o0 + 4]);
      *reinterpret_cast<float4*>(&wv[8])  = *reinterpret_cast<const float4*>(&lwTS[c * 64 + o0 + 8]);
      *reinterpret_cast<float4*>(&wv[12]) = *reinterpret_cast<const float4*>(&lwTS[c * 64 + o0 + 12]);
#pragma unroll
      for (int u = 0; u < 16; ++u) {
        accz[0][u] += a0 * wv[u];
        accz[1][u] += a1 * wv[u];
        accz[2][u] += a2 * wv[u];
        accz[3][u] += a3 * wv[u];
      }
    }

    // all ds_reads of cbuf retired -> safe to re-stage it with band kb+2
    asm volatile("s_waitcnt lgkmcnt(0)" ::: "memory");
    __builtin_amdgcn_sched_barrier(0);
    if (kb < NBAND - 2) stage_com(cbuf, cbase + (size_t)(kb + 2) * (NC * NC), lane);

    // sigmoid in place -> z
    const float ck = cwS[kb], dk = cbS[kb];
#pragma unroll
    for (int s = 0; s < 4; ++s)
#pragma unroll
      for (int u = 0; u < 16; ++u) {
        const float zv = ck * accz[s][u] + dk * rsumS[o0 + u] + lbS[o0 + u];
        accz[s][u] = 1.f / (1.f + __expf(-zv));
      }

    // scorer: per h, per-row partials over own 16 cols, 4-lane xor reduce;
    // lane q finishes rows rq+16*q via distributed tanh
    float sacc = 0.f;
#pragma unroll
    for (int h = 0; h < NHID; ++h) {
      float p0 = 0.f, p1 = 0.f, p2 = 0.f, p3 = 0.f;
#pragma unroll
      for (int u = 0; u < 16; ++u) {
        const float wh = w1S[h * 64 + o0 + u];
        p0 += accz[0][u] * wh;
        p1 += accz[1][u] * wh;
        p2 += accz[2][u] * wh;
        p3 += accz[3][u] * wh;
      }
      p0 += __shfl_xor(p0, 1, 64); p0 += __shfl_xor(p0, 2, 64);
      p1 += __shfl_xor(p1, 1, 64); p1 += __shfl_xor(p1, 2, 64);
      p2 += __shfl_xor(p2, 1, 64); p2 += __shfl_xor(p2, 2, 64);
      p3 += __shfl_xor(p3, 1, 64); p3 += __shfl_xor(p3, 2, 64);
      const float Ysel = (q == 0) ? p0 : (q == 1) ? p1 : (q == 2) ? p2 : p3;
      const float ex = __expf(2.f * (Ysel + b1S[h]));
      sacc += w2S[h] * (1.f - 2.f / (ex + 1.f));   // tanh
    }
    // broadcast the 4 row scores within the 4-lane group
    const int gbase = lane & 60;
    float sc[4];
#pragma unroll
    for (int s = 0; s < 4; ++s) sc[s] = __shfl(sacc, gbase + s, 64);

    // online softmax accumulate (per row)
#pragma unroll
    for (int s = 0; s < 4; ++s) {
      const float nm = fmaxf(mrun[s], sc[s]);
      const float f = __expf(mrun[s] - nm), e = __expf(sc[s] - nm);
      denom[s] = denom[s] * f + e;
#pragma unroll
      for (int u = 0; u < 16; ++u) oacc[s][u] = oacc[s][u] * f + e * accz[s][u];
      mrun[s] = nm;
    }
  }

  // store (float2: row base 62 floats -> 8B aligned)
#pragma unroll
  for (int s = 0; s < 4; ++s) {
    const int r = rq + 16 * s;
    if (r < NC) {
      const float inv = 1.f / denom[s];
      float* rowp = outp + (size_t)b * (NC * NC) + r * NC + o0;
      const int ne = (q < 3) ? 8 : 7;   // cols 48..61 for q==3
#pragma unroll
      for (int e = 0; e < 8; ++e)
        if (e < ne)
          *reinterpret_cast<float2*>(rowp + 2 * e) =
              make_float2(oacc[s][2 * e] * inv, oacc[s][2 * e + 1] * inv);
    }
  }
}

// =====================================================================
// Kernel C: Chebyshev GCN (both adjacencies, shared de@gc_w), feature,
// and the 992->62 FC. wnorm == 1 exactly; relu((h+e)/2) no-op on relu'd h,e.
// =====================================================================
__global__ __launch_bounds__(256) void k_cheb_fc(
    const float* __restrict__ de, const float* __restrict__ hidden,
    const float* __restrict__ essential, const float* __restrict__ gc_w,
    const float* __restrict__ gc_b, const float* __restrict__ fc_w,
    const float* __restrict__ fc_b, float* __restrict__ zmat) {
  const int b = blockIdx.x;
  __shared__ float hidS[NC * NC], essS[NC * NC];
  __shared__ float t0S[NC * NOUT], t1S[NC * NOUT];
  __shared__ float featS[NC * NOUT];
  __shared__ float deS[NC * NBAND];
  __shared__ float red2[256];
  const int tid = threadIdx.x;

  for (int t = tid; t < NC * NBAND; t += 256) deS[t] = de[b * NC * NBAND + t];
  for (int t = tid; t < NC * NC; t += 256) {
    hidS[t] = hidden[b * NC * NC + t];
    essS[t] = essential[b * NC * NC + t];
  }
  __syncthreads();
  for (int t = tid; t < NC * NOUT; t += 256) {
    const int i = t / NOUT, f = t % NOUT;
    float a0 = gc_b[f];
    float a1 = 0.f;
#pragma unroll
    for (int qq = 0; qq < NBAND; ++qq) {
      const float d = deS[i * NBAND + qq];
      a0 += d * gc_w[qq * NOUT + f];
      a1 += d * gc_w[(NBAND + qq) * NOUT + f];
    }
    t0S[t] = a0;
    t1S[t] = a1;
  }
  __syncthreads();
  for (int t = tid; t < NC * NOUT; t += 256) {
    const int i = t / NOUT, f = t % NOUT;
    float sh = 0.f, se = 0.f;
    for (int jj = 0; jj < NC; ++jj) {
      const float t1 = t1S[jj * NOUT + f];
      sh += hidS[i * NC + jj] * t1;
      se += essS[i * NC + jj] * t1;
    }
    const float gb1 = gc_b[NOUT + f];
    const float h = fmaxf(t0S[t] + sh + gb1, 0.f);
    const float e = fmaxf(t0S[t] + se + gb1, 0.f);
    featS[t] = 0.5f * (h + e);
  }
  __syncthreads();
  {
    const int n = tid >> 2, qq = tid & 3;
    float p = 0.f;
    if (n < NC) {
      const float* fw = fc_w + n * (NC * NOUT) + qq * 248;
      const float* fs = featS + qq * 248;
      for (int m = 0; m < 248; ++m) p += fs[m] * fw[m];
    }
    red2[tid] = p;
    __syncthreads();
    if (tid < NC) {
      const float z = red2[tid * 4] + red2[tid * 4 + 1] + red2[tid * 4 + 2] + red2[tid * 4 + 3] + fc_b[tid];
      zmat[b * NC + tid] = z;
    }
  }
}

// =====================================================================
// Kernel D1: batch-norm statistics (training-mode batch stats, ddof=0).
// =====================================================================
__global__ __launch_bounds__(256) void k_bnstats(
    const float* __restrict__ zmat, const float* __restrict__ bn_g,
    const float* __restrict__ bn_b, float* __restrict__ bnp) {
  const int n = blockIdx.x;
  __shared__ float rs[256], rq[256];
  const int tid = threadIdx.x;
  float s = 0.f, sq = 0.f;
  for (int r = tid; r < NB; r += 256) {
    const float v = zmat[r * NC + n];
    s += v;
    sq += v * v;
  }
  rs[tid] = s; rq[tid] = sq;
  __syncthreads();
  for (int st = 128; st > 0; st >>= 1) {
    if (tid < st) { rs[tid] += rs[tid + st]; rq[tid] += rq[tid + st]; }
    __syncthreads();
  }
  if (tid == 0) {
    const float mean = rs[0] * (1.f / NB);
    const float var = rq[0] * (1.f / NB) - mean * mean;
    const float sc = bn_g[n] * rsqrtf(var + 1e-5f);
    bnp[2 * n] = sc;
    bnp[2 * n + 1] = bn_b[n] - mean * sc;
  }
}

// =====================================================================
// Kernel D2: apply BN + sigmoid -> output1; 62->2 FC -> output.
// =====================================================================
__global__ __launch_bounds__(64) void k_bn_out(
    const float* __restrict__ zmat, const float* __restrict__ bnp,
    const float* __restrict__ fc4_w, const float* __restrict__ fc4_b,
    float* __restrict__ out) {
  const int b = blockIdx.x;
  const int lane = threadIdx.x;
  float o1 = 0.f;
  if (lane < NC) {
    float z = zmat[b * NC + lane];
    z = z * bnp[2 * lane] + bnp[2 * lane + 1];
    o1 = 1.f / (1.f + __expf(-z));
    out[b * NC + lane] = o1;
  }
  float p0 = (lane < NC) ? o1 * fc4_w[lane] : 0.f;
  float p1 = (lane < NC) ? o1 * fc4_w[NC + lane] : 0.f;
#pragma unroll
  for (int off = 32; off > 0; off >>= 1) {
    p0 += __shfl_down(p0, off, 64);
    p1 += __shfl_down(p1, off, 64);
  }
  if (lane == 0) {
    out[NB * NC + b * 2 + 0] = p0 + fc4_b[0];
    out[NB * NC + b * 2 + 1] = p1 + fc4_b[1];
  }
}

extern "C" void kernel_launch(void* const* d_in, const int* in_sizes, int n_in,
                              void* d_out, int out_size, void* d_ws, size_t ws_size,
                              hipStream_t stream) {
  const float* de      = (const float*)d_in[0];
  const float* pcc     = (const float*)d_in[1];
  const float* Aadj    = (const float*)d_in[2];
  // d_in[3] conv_w, d_in[4] conv_b: dead (gate cancels in trace-normalized SPD)
  const float* hconv_w = (const float*)d_in[5];
  const float* hconv_b = (const float*)d_in[6];
  const float* hlin_w  = (const float*)d_in[7];
  const float* hlin_b  = (const float*)d_in[8];
  const float* econv_w = (const float*)d_in[9];
  const float* econv_b = (const float*)d_in[10];
  const float* elin_w  = (const float*)d_in[11];
  const float* elin_b  = (const float*)d_in[12];
  const float* att_w1  = (const float*)d_in[13];
  const float* att_b1  = (const float*)d_in[14];
  const float* att_w2  = (const float*)d_in[15];
  const float* gc_w    = (const float*)d_in[16];
  const float* gc_b    = (const float*)d_in[17];
  // d_in[18] wpar: wnorm = exp(w)/exp(w) = 1 exactly for 1-element wpar
  const float* fc_w    = (const float*)d_in[19];
  const float* fc_b    = (const float*)d_in[20];
  const float* bn_g    = (const float*)d_in[21];
  const float* bn_b    = (const float*)d_in[22];
  const float* fc4_w   = (const float*)d_in[23];
  const float* fc4_b   = (const float*)d_in[24];

  float* ws        = (float*)d_ws;
  float* com       = ws;                                 // 19,681,280
  float* hidden    = com + (size_t)NB * NBAND * NC * NC; //  3,936,256
  float* essential = hidden + (size_t)NB * NC * NC;      //  3,936,256
  float* zmat      = essential + (size_t)NB * NC * NC;   //     63,488
  float* bnp       = zmat + (size_t)NB * NC;             //        128
  float* lwT       = bnp + 128;                          //      7,936 (2 x 62 x 64, zero-padded)
  float* rsumG     = lwT + 2 * NC * 64;                  //        128
  // total ~111 MB of workspace

  k_spd<<<NB * NBAND, 256, 0, stream>>>(pcc, Aadj, hlin_w, elin_w, com, lwT, rsumG);
  k_branch<<<NB * 2, 64, 0, stream>>>(com, lwT, rsumG,
      hconv_w, hconv_b, hlin_b,
      econv_w, econv_b, elin_b,
      att_w1, att_b1, att_w2, hidden, essential);
  k_cheb_fc<<<NB, 256, 0, stream>>>(de, hidden, essential, gc_w, gc_b, fc_w, fc_b, zmat);
  k_bnstats<<<NC, 256, 0, stream>>>(zmat, bn_g, bn_b, bnp);
  k_bn_out<<<NB, 64, 0, stream>>>(zmat, bnp, fc4_w, fc4_b, (float*)d_out);
}

// Round 6
// 275.634 us; speedup vs baseline: 1.3099x; 1.2911x over previous
//
#include <hip/hip_runtime.h>
#include <math.h>

#define NB    1024
#define NC    62
#define NBAND 5
#define NOUT  16
#define NHID  10
#define XSTR  68   // Xc row stride (mult of 4 for float4; 68%32=4 keeps conflicts 2-way)
#define CSTR  34   // k_branch chunk row stride (even: float2 writes; 34%32=2 -> <=2-way)

// =====================================================================
// Kernel A: gate-cancelled SPD.
//   relu(softmax(s)*x) = g*relu(x); cov/trace cancels g^2 and 1/(c-1):
//   com[b,k] = 0.5*(N(relu(pcc_t)) + N(relu(A))) + 1e-5*I,
//   N(X) = Xc^T Xc / ||Xc||_F^2, Xc row-centered. conv_w/conv_b dead.
// =====================================================================
__global__ __launch_bounds__(256) void k_spd(
    const float* __restrict__ pcc, const float* __restrict__ Aadj,
    const float* __restrict__ hlin_w, const float* __restrict__ elin_w,
    float* __restrict__ com, float* __restrict__ lwT, float* __restrict__ rsumG) {
  const int bk = (blockIdx.x & 7) * 640 + (blockIdx.x >> 3);  // XCD swizzle, 5120%8==0
  const int b = bk / NBAND, k = bk % NBAND;
  __shared__ __align__(16) float Xc[NC * XSTR];
  __shared__ float red4[4];
  const int tid = threadIdx.x;
  const int j = tid >> 2, q = tid & 3, o0 = q * 16;
  const int wave = tid >> 6, lane = tid & 63;
  const bool act = (j < NC);

  float ld[16];

  // ---- src0 = relu(pcc[b,:,:,k]) : row-per-group load
#pragma unroll
  for (int u = 0; u < 16; ++u) ld[u] = 0.f;
  if (act) {
    const float* src = pcc + ((size_t)(b * NC + j) * NC + o0) * NBAND + k;
#pragma unroll
    for (int u = 0; u < 16; ++u)
      if (o0 + u < NC) ld[u] = fmaxf(src[u * NBAND], 0.f);
  }
  float rs = 0.f;
#pragma unroll
  for (int u = 0; u < 16; ++u) rs += ld[u];
  rs += __shfl_xor(rs, 1, 64);
  rs += __shfl_xor(rs, 2, 64);
  const float m0 = rs * (1.f / NC);
  float sq = 0.f;
  if (act) {
#pragma unroll
    for (int u = 0; u < 16; ++u) {
      const float cv = (o0 + u < NC) ? (ld[u] - m0) : 0.f;
      Xc[j * XSTR + o0 + u] = cv;
      sq += cv * cv;
    }
  }
#pragma unroll
  for (int off = 1; off < 64; off <<= 1) sq += __shfl_xor(sq, off, 64);
  if (lane == 0) red4[wave] = sq;

  // prefetch src1 = Aadj[b,k] rows into regs (lands under SYRK0)
#pragma unroll
  for (int u = 0; u < 16; ++u) ld[u] = 0.f;
  if (act) {
    const float* src = Aadj + ((size_t)(b * NBAND + k) * NC + j) * NC + o0;
#pragma unroll
    for (int u = 0; u < 16; ++u)
      if (o0 + u < NC) ld[u] = src[u];
  }
  __syncthreads();   // (1) Xc0 + red4 ready

  // ---- SYRK0 with 4x4 tiles: G[4*tj+jj][4*tl+e]
  const int tj = tid >> 4, tl = tid & 15;
  float acc0[16];
#pragma unroll
  for (int u = 0; u < 16; ++u) acc0[u] = 0.f;
  for (int i = 0; i < NC; ++i) {
    float wj[4], wl[4];
    *reinterpret_cast<float4*>(wj) = *reinterpret_cast<const float4*>(&Xc[i * XSTR + 4 * tj]);
    *reinterpret_cast<float4*>(wl) = *reinterpret_cast<const float4*>(&Xc[i * XSTR + 4 * tl]);
#pragma unroll
    for (int jj = 0; jj < 4; ++jj)
#pragma unroll
      for (int e = 0; e < 4; ++e) acc0[jj * 4 + e] += wj[jj] * wl[e];
  }
  const float tra0 = red4[0] + red4[1] + red4[2] + red4[3];  // read BEFORE barrier (2)
  __syncthreads();   // (2) SYRK0 reads done; Xc/red4 reusable

  // ---- src1: relu + center in regs, write Xc
#pragma unroll
  for (int u = 0; u < 16; ++u) ld[u] = fmaxf(ld[u], 0.f);
  rs = 0.f;
#pragma unroll
  for (int u = 0; u < 16; ++u) rs += ld[u];
  rs += __shfl_xor(rs, 1, 64);
  rs += __shfl_xor(rs, 2, 64);
  const float m1 = rs * (1.f / NC);
  sq = 0.f;
  if (act) {
#pragma unroll
    for (int u = 0; u < 16; ++u) {
      const float cv = (o0 + u < NC) ? (ld[u] - m1) : 0.f;
      Xc[j * XSTR + o0 + u] = cv;
      sq += cv * cv;
    }
  }
#pragma unroll
  for (int off = 1; off < 64; off <<= 1) sq += __shfl_xor(sq, off, 64);
  if (lane == 0) red4[wave] = sq;
  __syncthreads();   // (3) Xc1 + red4 ready

  float acc1[16];
#pragma unroll
  for (int u = 0; u < 16; ++u) acc1[u] = 0.f;
  for (int i = 0; i < NC; ++i) {
    float wj[4], wl[4];
    *reinterpret_cast<float4*>(wj) = *reinterpret_cast<const float4*>(&Xc[i * XSTR + 4 * tj]);
    *reinterpret_cast<float4*>(wl) = *reinterpret_cast<const float4*>(&Xc[i * XSTR + 4 * tl]);
#pragma unroll
    for (int jj = 0; jj < 4; ++jj)
#pragma unroll
      for (int e = 0; e < 4; ++e) acc1[jj * 4 + e] += wj[jj] * wl[e];
  }
  const float tra1 = red4[0] + red4[1] + red4[2] + red4[3];

  // ---- combine + store (float2: rows are 62 floats -> only 8B-aligned)
  {
    const float s0 = 0.5f / tra0, s1 = 0.5f / tra1;
#pragma unroll
    for (int jj = 0; jj < 4; ++jj) {
      const int r = 4 * tj + jj;
      if (r < NC) {
        float v[4];
#pragma unroll
        for (int e = 0; e < 4; ++e) {
          v[e] = acc0[jj * 4 + e] * s0 + acc1[jj * 4 + e] * s1;
          if (tj == tl && jj == e) v[e] += 1e-5f;
        }
        float* rowp = com + (size_t)bk * (NC * NC) + r * NC + 4 * tl;
        if (tl < 15) {
          *reinterpret_cast<float2*>(rowp) = make_float2(v[0], v[1]);
          *reinterpret_cast<float2*>(rowp + 2) = make_float2(v[2], v[3]);
        } else {  // cols 60..63 -> only 60,61 valid
          *reinterpret_cast<float2*>(rowp) = make_float2(v[0], v[1]);
        }
      }
    }
  }

  // ---- block 0 epilogue: zero-padded lw transposes [c][o] + row sums
  if (blockIdx.x == 0) {
    for (int t = tid; t < NC * 64; t += 256) {
      const int c = t >> 6, o = t & 63;
      lwT[t]           = (o < NC) ? hlin_w[o * NC + c] : 0.f;
      lwT[NC * 64 + t] = (o < NC) ? elin_w[o * NC + c] : 0.f;
    }
    if (tid < 64) {
      float sh = 0.f, se = 0.f;
      if (tid < NC) {
        for (int c = 0; c < NC; ++c) { sh += hlin_w[tid * NC + c]; se += elin_w[tid * NC + c]; }
      }
      rsumG[tid] = sh;
      rsumG[64 + tid] = se;
    }
  }
}

// =====================================================================
// Kernel B (v6): 128-thread block (2 waves) per (b,br); wave w owns rows
// 32w..32w+31; thread (rq,q) tile = 2 rows x 16 cols (rows row0,row0+16,
// cols q*16..+15): 72 B LDS per 32 FMA. Band c-reduction split into two
// 32-col chunks double-buffered in comC[2][64x34] (17.4 KB) -> total LDS
// ~37 KB -> 4 blocks/CU = 8 waves/CU. Chunk staging is reg-staged T14
// (issue loads before GEMM, ds_write after, 1 barrier/chunk). Padded
// stride 34 keeps 16-row scalar reads conflict-free.
// half0 always uses comC[0], half1 comC[1] (fixed mapping, no index).
// =====================================================================
__global__ __launch_bounds__(128, 2) void k_branch(
    const float* __restrict__ com, const float* __restrict__ lwT,
    const float* __restrict__ rsumG,
    const float* __restrict__ hconv_w, const float* __restrict__ hconv_b,
    const float* __restrict__ hlin_b,
    const float* __restrict__ econv_w, const float* __restrict__ econv_b,
    const float* __restrict__ elin_b,
    const float* __restrict__ att_w1,  const float* __restrict__ att_b1,
    const float* __restrict__ att_w2,
    float* __restrict__ hiddenO, float* __restrict__ essentialO) {
  const int bid = (blockIdx.x & 7) * 256 + (blockIdx.x >> 3);  // XCD swizzle
  const int b = bid >> 1, br = bid & 1;

  const float* __restrict__ cw = br ? econv_w : hconv_w;
  const float* __restrict__ cb = br ? econv_b : hconv_b;
  const float* __restrict__ lb = br ? elin_b : hlin_b;
  float* __restrict__ outp = br ? essentialO : hiddenO;

  __shared__ __align__(16) float comC[2][64 * CSTR];  // 17.4 KB chunk dbuf
  __shared__ __align__(16) float lwTS[NC * 64];       // [c][o], zero-padded o>=62
  __shared__ float w1S[NHID * 64];                    // [h][o], zero-padded
  __shared__ float rsumS[64], lbS[64];
  __shared__ float b1S[16], w2S[16], cwS[8], cbS[8];

  const int tid = threadIdx.x;             // 0..127
  const int w = tid >> 6, lane = tid & 63;
  const int rq = lane >> 2, q = lane & 3, o0 = q * 16;
  const int row0 = w * 32 + rq;            // thread rows: row0, row0+16

  // staging geometry: wave w covers rows 32w..32w+31 of the 64x32 chunk;
  // per thread 4 row-segments of 4 floats (as 2 float2 each, 8B-aligned).
  const int srow = w * 32 + (lane >> 3);   // + i*8, i=0..3
  const int scc  = (lane & 7) * 4;
  const float* cbase = com + (size_t)(b * NBAND) * (NC * NC);

  float2 pf[8];
  auto stage_issue = [&](int band, int c0) {
    const float* bb = cbase + (size_t)band * (NC * NC);
#pragma unroll
    for (int i = 0; i < 4; ++i) {
      const int r = srow + i * 8;
      const int rsrc = (r < NC) ? r : (NC - 1);
      const float* p = bb + rsrc * NC + c0 + scc;
      pf[2 * i]     = *reinterpret_cast<const float2*>(p);
      pf[2 * i + 1] = *reinterpret_cast<const float2*>(p + 2);
    }
  };
  auto stage_write = [&](float* buf) {
#pragma unroll
    for (int i = 0; i < 4; ++i) {
      const int r = srow + i * 8;
      float* d = buf + r * CSTR + scc;    // even addr -> ds_write_b64
      *reinterpret_cast<float2*>(d)     = pf[2 * i];
      *reinterpret_cast<float2*>(d + 2) = pf[2 * i + 1];
    }
  };

  // ---- LDS fills
  {
    const float4* src = reinterpret_cast<const float4*>(lwT + br * (NC * 64));
    float4* dst = reinterpret_cast<float4*>(lwTS);
#pragma unroll
    for (int i = 0; i < 8; ++i) {
      const int idx = tid + i * 128;
      if (idx < NC * 16) dst[idx] = src[idx];   // 992 float4s
    }
  }
  for (int t = tid; t < NHID * 64; t += 128) {
    const int c = t & 63;
    w1S[t] = (c < NC) ? att_w1[(t >> 6) * NC + c] : 0.f;
  }
  if (tid < 64) {
    rsumS[tid] = rsumG[br * 64 + tid];
    lbS[tid] = (tid < NC) ? lb[tid] : 0.f;
  }
  if (tid < NHID) { b1S[tid] = att_b1[tid]; w2S[tid] = att_w2[tid]; }
  if (tid < NBAND) { cwS[tid] = cw[tid]; cbS[tid] = cb[tid]; }

  // stage chunk (band0, half0) -> comC[0]
  stage_issue(0, 0);
  stage_write(comC[0]);
  __syncthreads();

  float oacc[2][16];
#pragma unroll
  for (int s = 0; s < 2; ++s)
#pragma unroll
    for (int u = 0; u < 16; ++u) oacc[s][u] = 0.f;
  float denom[2] = {0.f, 0.f};
  float mrun[2] = {-1e30f, -1e30f};

#define GEMM_CHUNK(CBUF, C0G)                                                   \
  do {                                                                          \
    const float* cb_ = (CBUF);                                                  \
    _Pragma("unroll 4")                                                         \
    for (int cc = 0; cc < 32; ++cc) {                                           \
      const float a0 = cb_[row0 * CSTR + cc];                                   \
      const float a1 = cb_[(row0 + 16) * CSTR + cc];                            \
      const float* lwp = &lwTS[((C0G) + cc) * 64 + o0];                         \
      float wv[16];                                                             \
      *reinterpret_cast<float4*>(&wv[0])  = *reinterpret_cast<const float4*>(lwp + 0);  \
      *reinterpret_cast<float4*>(&wv[4])  = *reinterpret_cast<const float4*>(lwp + 4);  \
      *reinterpret_cast<float4*>(&wv[8])  = *reinterpret_cast<const float4*>(lwp + 8);  \
      *reinterpret_cast<float4*>(&wv[12]) = *reinterpret_cast<const float4*>(lwp + 12); \
      _Pragma("unroll")                                                         \
      for (int u = 0; u < 16; ++u) {                                            \
        accz[0][u] += a0 * wv[u];                                               \
        accz[1][u] += a1 * wv[u];                                               \
      }                                                                         \
    }                                                                           \
  } while (0)

#pragma unroll 1
  for (int kb = 0; kb < NBAND; ++kb) {
    float accz[2][16];
#pragma unroll
    for (int s = 0; s < 2; ++s)
#pragma unroll
      for (int u = 0; u < 16; ++u) accz[s][u] = 0.f;

    // ---- half 0: GEMM comC[0] (cols 0..31); stage (kb, half1) -> comC[1]
    stage_issue(kb, 32);
    GEMM_CHUNK(comC[0], 0);
    stage_write(comC[1]);
    __syncthreads();

    // ---- half 1: GEMM comC[1] (cols 32..63); stage (kb+1, half0) -> comC[0]
    if (kb < NBAND - 1) {
      stage_issue(kb + 1, 0);
      GEMM_CHUNK(comC[1], 32);
      stage_write(comC[0]);
      __syncthreads();
    } else {
      GEMM_CHUNK(comC[1], 32);
    }

    // ---- sigmoid in place -> z (accz reused)
    const float ck = cwS[kb], dk = cbS[kb];
#pragma unroll
    for (int s = 0; s < 2; ++s)
#pragma unroll
      for (int u = 0; u < 16; ++u) {
        const float zv = ck * accz[s][u] + dk * rsumS[o0 + u] + lbS[o0 + u];
        accz[s][u] = 1.f / (1.f + __expf(-zv));
      }

    // ---- scorer: paired-h parity trick, 5 tanh/lane, no divergence.
    // For t=0..4 compute row-sums for h=2t and h=2t+1 (all lanes), then
    // lane evaluates h = 2t+(q&1) for its row s = q>>1.
    float sacc = 0.f;
#pragma unroll
    for (int t = 0; t < 5; ++t) {
      const int hA = 2 * t, hB = 2 * t + 1;
      float pA0 = 0.f, pA1 = 0.f, pB0 = 0.f, pB1 = 0.f;
#pragma unroll
      for (int u = 0; u < 16; ++u) {
        const float whA = w1S[hA * 64 + o0 + u];
        const float whB = w1S[hB * 64 + o0 + u];
        pA0 += accz[0][u] * whA;
        pA1 += accz[1][u] * whA;
        pB0 += accz[0][u] * whB;
        pB1 += accz[1][u] * whB;
      }
      pA0 += __shfl_xor(pA0, 1, 64); pA0 += __shfl_xor(pA0, 2, 64);
      pA1 += __shfl_xor(pA1, 1, 64); pA1 += __shfl_xor(pA1, 2, 64);
      pB0 += __shfl_xor(pB0, 1, 64); pB0 += __shfl_xor(pB0, 2, 64);
      pB1 += __shfl_xor(pB1, 1, 64); pB1 += __shfl_xor(pB1, 2, 64);
      const int hm = hA + (q & 1);                 // my h
      const float pSelA = (q >> 1) ? pA1 : pA0;    // my row, h=hA
      const float pSelB = (q >> 1) ? pB1 : pB0;    // my row, h=hB
      const float pm = (q & 1) ? pSelB : pSelA;
      const float ex = __expf(2.f * (pm + b1S[hm]));
      sacc += w2S[hm] * (1.f - 2.f / (ex + 1.f));  // w2[hm]*tanh(pm+b1[hm])
    }
    // combine the two parity halves: lanes {q=0,1} -> row s=0; {2,3} -> s=1
    sacc += __shfl_xor(sacc, 1, 64);
    const int gbase = lane & 60;
    float sc[2];
    sc[0] = __shfl(sacc, gbase + 0, 64);
    sc[1] = __shfl(sacc, gbase + 2, 64);

    // ---- online softmax accumulate (per row)
#pragma unroll
    for (int s = 0; s < 2; ++s) {
      const float nm = fmaxf(mrun[s], sc[s]);
      const float f = __expf(mrun[s] - nm), e = __expf(sc[s] - nm);
      denom[s] = denom[s] * f + e;
#pragma unroll
      for (int u = 0; u < 16; ++u) oacc[s][u] = oacc[s][u] * f + e * accz[s][u];
      mrun[s] = nm;
    }
  }
#undef GEMM_CHUNK

  // ---- store (float2: row base 62 floats -> 8B aligned)
#pragma unroll
  for (int s = 0; s < 2; ++s) {
    const int r = row0 + 16 * s;
    if (r < NC) {
      const float inv = 1.f / denom[s];
      float* rowp = outp + (size_t)b * (NC * NC) + r * NC + o0;
      const int ne = (q < 3) ? 8 : 7;   // cols 48..61 for q==3
#pragma unroll
      for (int e = 0; e < 8; ++e)
        if (e < ne)
          *reinterpret_cast<float2*>(rowp + 2 * e) =
              make_float2(oacc[s][2 * e] * inv, oacc[s][2 * e + 1] * inv);
    }
  }
}

// =====================================================================
// Kernel C: Chebyshev GCN (both adjacencies, shared de@gc_w), feature,
// and the 992->62 FC. wnorm == 1 exactly; relu((h+e)/2) no-op on relu'd h,e.
// =====================================================================
__global__ __launch_bounds__(256) void k_cheb_fc(
    const float* __restrict__ de, const float* __restrict__ hidden,
    const float* __restrict__ essential, const float* __restrict__ gc_w,
    const float* __restrict__ gc_b, const float* __restrict__ fc_w,
    const float* __restrict__ fc_b, float* __restrict__ zmat) {
  const int b = blockIdx.x;
  __shared__ float hidS[NC * NC], essS[NC * NC];
  __shared__ float t0S[NC * NOUT], t1S[NC * NOUT];
  __shared__ float featS[NC * NOUT];
  __shared__ float deS[NC * NBAND];
  __shared__ float red2[256];
  const int tid = threadIdx.x;

  for (int t = tid; t < NC * NBAND; t += 256) deS[t] = de[b * NC * NBAND + t];
  for (int t = tid; t < NC * NC; t += 256) {
    hidS[t] = hidden[b * NC * NC + t];
    essS[t] = essential[b * NC * NC + t];
  }
  __syncthreads();
  for (int t = tid; t < NC * NOUT; t += 256) {
    const int i = t / NOUT, f = t % NOUT;
    float a0 = gc_b[f];
    float a1 = 0.f;
#pragma unroll
    for (int qq = 0; qq < NBAND; ++qq) {
      const float d = deS[i * NBAND + qq];
      a0 += d * gc_w[qq * NOUT + f];
      a1 += d * gc_w[(NBAND + qq) * NOUT + f];
    }
    t0S[t] = a0;
    t1S[t] = a1;
  }
  __syncthreads();
  for (int t = tid; t < NC * NOUT; t += 256) {
    const int i = t / NOUT, f = t % NOUT;
    float sh = 0.f, se = 0.f;
    for (int jj = 0; jj < NC; ++jj) {
      const float t1 = t1S[jj * NOUT + f];
      sh += hidS[i * NC + jj] * t1;
      se += essS[i * NC + jj] * t1;
    }
    const float gb1 = gc_b[NOUT + f];
    const float h = fmaxf(t0S[t] + sh + gb1, 0.f);
    const float e = fmaxf(t0S[t] + se + gb1, 0.f);
    featS[t] = 0.5f * (h + e);
  }
  __syncthreads();
  {
    const int n = tid >> 2, qq = tid & 3;
    float p = 0.f;
    if (n < NC) {
      const float* fw = fc_w + n * (NC * NOUT) + qq * 248;
      const float* fs = featS + qq * 248;
      for (int m = 0; m < 248; ++m) p += fs[m] * fw[m];
    }
    red2[tid] = p;
    __syncthreads();
    if (tid < NC) {
      const float z = red2[tid * 4] + red2[tid * 4 + 1] + red2[tid * 4 + 2] + red2[tid * 4 + 3] + fc_b[tid];
      zmat[b * NC + tid] = z;
    }
  }
}

// =====================================================================
// Kernel D1: batch-norm statistics (training-mode batch stats, ddof=0).
// =====================================================================
__global__ __launch_bounds__(256) void k_bnstats(
    const float* __restrict__ zmat, const float* __restrict__ bn_g,
    const float* __restrict__ bn_b, float* __restrict__ bnp) {
  const int n = blockIdx.x;
  __shared__ float rs[256], rq[256];
  const int tid = threadIdx.x;
  float s = 0.f, sq = 0.f;
  for (int r = tid; r < NB; r += 256) {
    const float v = zmat[r * NC + n];
    s += v;
    sq += v * v;
  }
  rs[tid] = s; rq[tid] = sq;
  __syncthreads();
  for (int st = 128; st > 0; st >>= 1) {
    if (tid < st) { rs[tid] += rs[tid + st]; rq[tid] += rq[tid + st]; }
    __syncthreads();
  }
  if (tid == 0) {
    const float mean = rs[0] * (1.f / NB);
    const float var = rq[0] * (1.f / NB) - mean * mean;
    const float sc = bn_g[n] * rsqrtf(var + 1e-5f);
    bnp[2 * n] = sc;
    bnp[2 * n + 1] = bn_b[n] - mean * sc;
  }
}

// =====================================================================
// Kernel D2: apply BN + sigmoid -> output1; 62->2 FC -> output.
// =====================================================================
__global__ __launch_bounds__(64) void k_bn_out(
    const float* __restrict__ zmat, const float* __restrict__ bnp,
    const float* __restrict__ fc4_w, const float* __restrict__ fc4_b,
    float* __restrict__ out) {
  const int b = blockIdx.x;
  const int lane = threadIdx.x;
  float o1 = 0.f;
  if (lane < NC) {
    float z = zmat[b * NC + lane];
    z = z * bnp[2 * lane] + bnp[2 * lane + 1];
    o1 = 1.f / (1.f + __expf(-z));
    out[b * NC + lane] = o1;
  }
  float p0 = (lane < NC) ? o1 * fc4_w[lane] : 0.f;
  float p1 = (lane < NC) ? o1 * fc4_w[NC + lane] : 0.f;
#pragma unroll
  for (int off = 32; off > 0; off >>= 1) {
    p0 += __shfl_down(p0, off, 64);
    p1 += __shfl_down(p1, off, 64);
  }
  if (lane == 0) {
    out[NB * NC + b * 2 + 0] = p0 + fc4_b[0];
    out[NB * NC + b * 2 + 1] = p1 + fc4_b[1];
  }
}

extern "C" void kernel_launch(void* const* d_in, const int* in_sizes, int n_in,
                              void* d_out, int out_size, void* d_ws, size_t ws_size,
                              hipStream_t stream) {
  const float* de      = (const float*)d_in[0];
  const float* pcc     = (const float*)d_in[1];
  const float* Aadj    = (const float*)d_in[2];
  // d_in[3] conv_w, d_in[4] conv_b: dead (gate cancels in trace-normalized SPD)
  const float* hconv_w = (const float*)d_in[5];
  const float* hconv_b = (const float*)d_in[6];
  const float* hlin_w  = (const float*)d_in[7];
  const float* hlin_b  = (const float*)d_in[8];
  const float* econv_w = (const float*)d_in[9];
  const float* econv_b = (const float*)d_in[10];
  const float* elin_w  = (const float*)d_in[11];
  const float* elin_b  = (const float*)d_in[12];
  const float* att_w1  = (const float*)d_in[13];
  const float* att_b1  = (const float*)d_in[14];
  const float* att_w2  = (const float*)d_in[15];
  const float* gc_w    = (const float*)d_in[16];
  const float* gc_b    = (const float*)d_in[17];
  // d_in[18] wpar: wnorm = exp(w)/exp(w) = 1 exactly for 1-element wpar
  const float* fc_w    = (const float*)d_in[19];
  const float* fc_b    = (const float*)d_in[20];
  const float* bn_g    = (const float*)d_in[21];
  const float* bn_b    = (const float*)d_in[22];
  const float* fc4_w   = (const float*)d_in[23];
  const float* fc4_b   = (const float*)d_in[24];

  float* ws        = (float*)d_ws;
  float* com       = ws;                                 // 19,681,280
  float* hidden    = com + (size_t)NB * NBAND * NC * NC; //  3,936,256
  float* essential = hidden + (size_t)NB * NC * NC;      //  3,936,256
  float* zmat      = essential + (size_t)NB * NC * NC;   //     63,488
  float* bnp       = zmat + (size_t)NB * NC;             //        128
  float* lwT       = bnp + 128;                          //      7,936 (2 x 62 x 64, zero-padded)
  float* rsumG     = lwT + 2 * NC * 64;                  //        128
  // total ~111 MB of workspace

  k_spd<<<NB * NBAND, 256, 0, stream>>>(pcc, Aadj, hlin_w, elin_w, com, lwT, rsumG);
  k_branch<<<NB * 2, 128, 0, stream>>>(com, lwT, rsumG,
      hconv_w, hconv_b, hlin_b,
      econv_w, econv_b, elin_b,
      att_w1, att_b1, att_w2, hidden, essential);
  k_cheb_fc<<<NB, 256, 0, stream>>>(de, hidden, essential, gc_w, gc_b, fc_w, fc_b, zmat);
  k_bnstats<<<NC, 256, 0, stream>>>(zmat, bn_g, bn_b, bnp);
  k_bn_out<<<NB, 64, 0, stream>>>(zmat, bnp, fc4_w, fc4_b, (float*)d_out);
}

// Round 7
// 266.965 us; speedup vs baseline: 1.3524x; 1.0325x over previous
//
#include <hip/hip_runtime.h>
#include <math.h>

#define NB    1024
#define NC    62
#define NBAND 5
#define NOUT  16
#define NHID  10
#define XSTR  68   // Xc row stride (mult of 4 for float4; 68%32=4 keeps conflicts 2-way)
#define CSTR  34   // k_branch chunk row stride (even: float2 writes; 34%32=2 -> <=2-way)

typedef __attribute__((ext_vector_type(2))) float f32x2;
#define FMA2(a, b, c) __builtin_elementwise_fma((a), (b), (c))

// =====================================================================
// Kernel A: gate-cancelled SPD.
//   relu(softmax(s)*x) = g*relu(x); cov/trace cancels g^2 and 1/(c-1):
//   com[b,k] = 0.5*(N(relu(pcc_t)) + N(relu(A))) + 1e-5*I,
//   N(X) = Xc^T Xc / ||Xc||_F^2, Xc row-centered. conv_w/conv_b dead.
// SYRK uses v_pk_fma_f32 (f32x2): 8 pk-FMA per i-step per thread.
// =====================================================================
__global__ __launch_bounds__(256) void k_spd(
    const float* __restrict__ pcc, const float* __restrict__ Aadj,
    const float* __restrict__ hlin_w, const float* __restrict__ elin_w,
    float* __restrict__ com, float* __restrict__ lwT, float* __restrict__ rsumG) {
  const int bk = (blockIdx.x & 7) * 640 + (blockIdx.x >> 3);  // XCD swizzle, 5120%8==0
  const int b = bk / NBAND, k = bk % NBAND;
  __shared__ __align__(16) float Xc[NC * XSTR];
  __shared__ float red4[4];
  const int tid = threadIdx.x;
  const int j = tid >> 2, q = tid & 3, o0 = q * 16;
  const int wave = tid >> 6, lane = tid & 63;
  const bool act = (j < NC);

  float ld[16];

  // ---- src0 = relu(pcc[b,:,:,k]) : row-per-group load
#pragma unroll
  for (int u = 0; u < 16; ++u) ld[u] = 0.f;
  if (act) {
    const float* src = pcc + ((size_t)(b * NC + j) * NC + o0) * NBAND + k;
#pragma unroll
    for (int u = 0; u < 16; ++u)
      if (o0 + u < NC) ld[u] = fmaxf(src[u * NBAND], 0.f);
  }
  float rs = 0.f;
#pragma unroll
  for (int u = 0; u < 16; ++u) rs += ld[u];
  rs += __shfl_xor(rs, 1, 64);
  rs += __shfl_xor(rs, 2, 64);
  const float m0 = rs * (1.f / NC);
  float sq = 0.f;
  if (act) {
#pragma unroll
    for (int u = 0; u < 16; ++u) {
      const float cv = (o0 + u < NC) ? (ld[u] - m0) : 0.f;
      Xc[j * XSTR + o0 + u] = cv;
      sq += cv * cv;
    }
  }
#pragma unroll
  for (int off = 1; off < 64; off <<= 1) sq += __shfl_xor(sq, off, 64);
  if (lane == 0) red4[wave] = sq;

  // prefetch src1 = Aadj[b,k] rows into regs (lands under SYRK0)
#pragma unroll
  for (int u = 0; u < 16; ++u) ld[u] = 0.f;
  if (act) {
    const float* src = Aadj + ((size_t)(b * NBAND + k) * NC + j) * NC + o0;
#pragma unroll
    for (int u = 0; u < 16; ++u)
      if (o0 + u < NC) ld[u] = src[u];
  }
  __syncthreads();   // (1) Xc0 + red4 ready

  // ---- SYRK0 with 4x4 tiles (packed): G[4*tj+jj][4*tl+e]
  const int tj = tid >> 4, tl = tid & 15;
  f32x2 acc0p[8], acc1p[8];
#pragma unroll
  for (int u = 0; u < 8; ++u) acc0p[u] = (f32x2){0.f, 0.f};
  for (int i = 0; i < NC; ++i) {
    const float4 wjv = *reinterpret_cast<const float4*>(&Xc[i * XSTR + 4 * tj]);
    const float4 wlv = *reinterpret_cast<const float4*>(&Xc[i * XSTR + 4 * tl]);
    const f32x2 wl01 = {wlv.x, wlv.y}, wl23 = {wlv.z, wlv.w};
    const float wj4[4] = {wjv.x, wjv.y, wjv.z, wjv.w};
#pragma unroll
    for (int jj = 0; jj < 4; ++jj) {
      const f32x2 s = {wj4[jj], wj4[jj]};
      acc0p[jj * 2 + 0] = FMA2(s, wl01, acc0p[jj * 2 + 0]);
      acc0p[jj * 2 + 1] = FMA2(s, wl23, acc0p[jj * 2 + 1]);
    }
  }
  const float tra0 = red4[0] + red4[1] + red4[2] + red4[3];  // read BEFORE barrier (2)
  __syncthreads();   // (2) SYRK0 reads done; Xc/red4 reusable

  // ---- src1: relu + center in regs, write Xc
#pragma unroll
  for (int u = 0; u < 16; ++u) ld[u] = fmaxf(ld[u], 0.f);
  rs = 0.f;
#pragma unroll
  for (int u = 0; u < 16; ++u) rs += ld[u];
  rs += __shfl_xor(rs, 1, 64);
  rs += __shfl_xor(rs, 2, 64);
  const float m1 = rs * (1.f / NC);
  sq = 0.f;
  if (act) {
#pragma unroll
    for (int u = 0; u < 16; ++u) {
      const float cv = (o0 + u < NC) ? (ld[u] - m1) : 0.f;
      Xc[j * XSTR + o0 + u] = cv;
      sq += cv * cv;
    }
  }
#pragma unroll
  for (int off = 1; off < 64; off <<= 1) sq += __shfl_xor(sq, off, 64);
  if (lane == 0) red4[wave] = sq;
  __syncthreads();   // (3) Xc1 + red4 ready

#pragma unroll
  for (int u = 0; u < 8; ++u) acc1p[u] = (f32x2){0.f, 0.f};
  for (int i = 0; i < NC; ++i) {
    const float4 wjv = *reinterpret_cast<const float4*>(&Xc[i * XSTR + 4 * tj]);
    const float4 wlv = *reinterpret_cast<const float4*>(&Xc[i * XSTR + 4 * tl]);
    const f32x2 wl01 = {wlv.x, wlv.y}, wl23 = {wlv.z, wlv.w};
    const float wj4[4] = {wjv.x, wjv.y, wjv.z, wjv.w};
#pragma unroll
    for (int jj = 0; jj < 4; ++jj) {
      const f32x2 s = {wj4[jj], wj4[jj]};
      acc1p[jj * 2 + 0] = FMA2(s, wl01, acc1p[jj * 2 + 0]);
      acc1p[jj * 2 + 1] = FMA2(s, wl23, acc1p[jj * 2 + 1]);
    }
  }
  const float tra1 = red4[0] + red4[1] + red4[2] + red4[3];

  // ---- combine + store (f32x2: rows are 62 floats -> 8B-aligned)
  {
    const float s0 = 0.5f / tra0, s1 = 0.5f / tra1;
    const f32x2 s0v = {s0, s0}, s1v = {s1, s1};
#pragma unroll
    for (int jj = 0; jj < 4; ++jj) {
      const int r = 4 * tj + jj;
      if (r < NC) {
        f32x2 v01 = FMA2(acc1p[jj * 2 + 0], s1v, acc0p[jj * 2 + 0] * s0v);
        f32x2 v23 = FMA2(acc1p[jj * 2 + 1], s1v, acc0p[jj * 2 + 1] * s0v);
        if (tj == tl) {   // diagonal element e == jj
          if (jj == 0) v01[0] += 1e-5f;
          if (jj == 1) v01[1] += 1e-5f;
          if (jj == 2) v23[0] += 1e-5f;
          if (jj == 3) v23[1] += 1e-5f;
        }
        float* rowp = com + (size_t)bk * (NC * NC) + r * NC + 4 * tl;
        *reinterpret_cast<f32x2*>(rowp) = v01;
        if (tl < 15) *reinterpret_cast<f32x2*>(rowp + 2) = v23;  // cols 62/63 don't exist
      }
    }
  }

  // ---- block 0 epilogue: zero-padded lw transposes [c][o] + row sums
  if (blockIdx.x == 0) {
    for (int t = tid; t < NC * 64; t += 256) {
      const int c = t >> 6, o = t & 63;
      lwT[t]           = (o < NC) ? hlin_w[o * NC + c] : 0.f;
      lwT[NC * 64 + t] = (o < NC) ? elin_w[o * NC + c] : 0.f;
    }
    if (tid < 64) {
      float sh = 0.f, se = 0.f;
      if (tid < NC) {
        for (int c = 0; c < NC; ++c) { sh += hlin_w[tid * NC + c]; se += elin_w[tid * NC + c]; }
      }
      rsumG[tid] = sh;
      rsumG[64 + tid] = se;
    }
  }
}

// =====================================================================
// Kernel B (v7): v6 structure (2-wave blocks, 32-col chunk dbuf, T14
// reg-staging) with ALL hot math on v_pk_fma_f32 (f32x2):
// GEMM 16 pk-FMA/c-step, scorer 4x8 pk + b64 w1 loads, packed sigmoid
// pre-activation and online-softmax accumulate.
// =====================================================================
__global__ __launch_bounds__(128, 2) void k_branch(
    const float* __restrict__ com, const float* __restrict__ lwT,
    const float* __restrict__ rsumG,
    const float* __restrict__ hconv_w, const float* __restrict__ hconv_b,
    const float* __restrict__ hlin_b,
    const float* __restrict__ econv_w, const float* __restrict__ econv_b,
    const float* __restrict__ elin_b,
    const float* __restrict__ att_w1,  const float* __restrict__ att_b1,
    const float* __restrict__ att_w2,
    float* __restrict__ hiddenO, float* __restrict__ essentialO) {
  const int bid = (blockIdx.x & 7) * 256 + (blockIdx.x >> 3);  // XCD swizzle
  const int b = bid >> 1, br = bid & 1;

  const float* __restrict__ cw = br ? econv_w : hconv_w;
  const float* __restrict__ cb = br ? econv_b : hconv_b;
  const float* __restrict__ lb = br ? elin_b : hlin_b;
  float* __restrict__ outp = br ? essentialO : hiddenO;

  __shared__ __align__(16) float comC[2][64 * CSTR];  // 17.4 KB chunk dbuf
  __shared__ __align__(16) float lwTS[NC * 64];       // [c][o], zero-padded o>=62
  __shared__ __align__(8)  float w1S[NHID * 64];      // [h][o], zero-padded
  __shared__ __align__(8)  float rsumS[64], lbS[64];
  __shared__ float b1S[16], w2S[16], cwS[8], cbS[8];

  const int tid = threadIdx.x;             // 0..127
  const int w = tid >> 6, lane = tid & 63;
  const int rq = lane >> 2, q = lane & 3, o0 = q * 16;
  const int row0 = w * 32 + rq;            // thread rows: row0, row0+16

  // staging geometry: wave w covers rows 32w..32w+31 of the 64x32 chunk.
  const int srow = w * 32 + (lane >> 3);   // + i*8, i=0..3
  const int scc  = (lane & 7) * 4;
  const float* cbase = com + (size_t)(b * NBAND) * (NC * NC);

  float2 pf[8];
  auto stage_issue = [&](int band, int c0) {
    const float* bb = cbase + (size_t)band * (NC * NC);
#pragma unroll
    for (int i = 0; i < 4; ++i) {
      const int r = srow + i * 8;
      const int rsrc = (r < NC) ? r : (NC - 1);
      const float* p = bb + rsrc * NC + c0 + scc;
      pf[2 * i]     = *reinterpret_cast<const float2*>(p);
      pf[2 * i + 1] = *reinterpret_cast<const float2*>(p + 2);
    }
  };
  auto stage_write = [&](float* buf) {
#pragma unroll
    for (int i = 0; i < 4; ++i) {
      const int r = srow + i * 8;
      float* d = buf + r * CSTR + scc;    // even addr -> ds_write_b64
      *reinterpret_cast<float2*>(d)     = pf[2 * i];
      *reinterpret_cast<float2*>(d + 2) = pf[2 * i + 1];
    }
  };

  // ---- LDS fills
  {
    const float4* src = reinterpret_cast<const float4*>(lwT + br * (NC * 64));
    float4* dst = reinterpret_cast<float4*>(lwTS);
#pragma unroll
    for (int i = 0; i < 8; ++i) {
      const int idx = tid + i * 128;
      if (idx < NC * 16) dst[idx] = src[idx];   // 992 float4s
    }
  }
  for (int t = tid; t < NHID * 64; t += 128) {
    const int c = t & 63;
    w1S[t] = (c < NC) ? att_w1[(t >> 6) * NC + c] : 0.f;
  }
  if (tid < 64) {
    rsumS[tid] = rsumG[br * 64 + tid];
    lbS[tid] = (tid < NC) ? lb[tid] : 0.f;
  }
  if (tid < NHID) { b1S[tid] = att_b1[tid]; w2S[tid] = att_w2[tid]; }
  if (tid < NBAND) { cwS[tid] = cw[tid]; cbS[tid] = cb[tid]; }

  // stage chunk (band0, half0) -> comC[0]
  stage_issue(0, 0);
  stage_write(comC[0]);
  __syncthreads();

  f32x2 oacc2[2][8];
#pragma unroll
  for (int s = 0; s < 2; ++s)
#pragma unroll
    for (int u = 0; u < 8; ++u) oacc2[s][u] = (f32x2){0.f, 0.f};
  float denom[2] = {0.f, 0.f};
  float mrun[2] = {-1e30f, -1e30f};

  f32x2 accz2[2][8];
  auto gemm_chunk = [&](const float* cb_, int c0g) {
#pragma unroll 4
    for (int cc = 0; cc < 32; ++cc) {
      const float a0 = cb_[row0 * CSTR + cc];
      const float a1 = cb_[(row0 + 16) * CSTR + cc];
      const f32x2 a0v = {a0, a0}, a1v = {a1, a1};
      const float* lwp = &lwTS[(c0g + cc) * 64 + o0];
      const float4 t0 = *reinterpret_cast<const float4*>(lwp + 0);
      const float4 t1 = *reinterpret_cast<const float4*>(lwp + 4);
      const float4 t2 = *reinterpret_cast<const float4*>(lwp + 8);
      const float4 t3 = *reinterpret_cast<const float4*>(lwp + 12);
      const f32x2 wv[8] = {{t0.x, t0.y}, {t0.z, t0.w}, {t1.x, t1.y}, {t1.z, t1.w},
                           {t2.x, t2.y}, {t2.z, t2.w}, {t3.x, t3.y}, {t3.z, t3.w}};
#pragma unroll
      for (int u = 0; u < 8; ++u) {
        accz2[0][u] = FMA2(a0v, wv[u], accz2[0][u]);
        accz2[1][u] = FMA2(a1v, wv[u], accz2[1][u]);
      }
    }
  };

#pragma unroll 1
  for (int kb = 0; kb < NBAND; ++kb) {
#pragma unroll
    for (int s = 0; s < 2; ++s)
#pragma unroll
      for (int u = 0; u < 8; ++u) accz2[s][u] = (f32x2){0.f, 0.f};

    // ---- half 0: GEMM comC[0] (cols 0..31); stage (kb, half1) -> comC[1]
    stage_issue(kb, 32);
    gemm_chunk(comC[0], 0);
    stage_write(comC[1]);
    __syncthreads();

    // ---- half 1: GEMM comC[1] (cols 32..63); stage (kb+1, half0) -> comC[0]
    if (kb < NBAND - 1) {
      stage_issue(kb + 1, 0);
      gemm_chunk(comC[1], 32);
      stage_write(comC[0]);
      __syncthreads();
    } else {
      gemm_chunk(comC[1], 32);
    }

    // ---- sigmoid in place -> z (packed pre-activation)
    {
      const float ck = cwS[kb], dk = cbS[kb];
      const f32x2 ckv = {ck, ck}, dkv = {dk, dk};
      const f32x2* rs2 = reinterpret_cast<const f32x2*>(&rsumS[o0]);
      const f32x2* lb2 = reinterpret_cast<const f32x2*>(&lbS[o0]);
      f32x2 basev[8];
#pragma unroll
      for (int u = 0; u < 8; ++u) basev[u] = FMA2(dkv, rs2[u], lb2[u]);
#pragma unroll
      for (int s = 0; s < 2; ++s)
#pragma unroll
        for (int u = 0; u < 8; ++u) {
          const f32x2 zv = FMA2(ckv, accz2[s][u], basev[u]);
          accz2[s][u][0] = 1.f / (1.f + __expf(-zv[0]));
          accz2[s][u][1] = 1.f / (1.f + __expf(-zv[1]));
        }
    }

    // ---- scorer: paired-h parity trick (packed partials, b64 w1 loads)
    float sacc = 0.f;
#pragma unroll
    for (int t = 0; t < 5; ++t) {
      const int hA = 2 * t, hB = 2 * t + 1;
      const f32x2* wA = reinterpret_cast<const f32x2*>(&w1S[hA * 64 + o0]);
      const f32x2* wB = reinterpret_cast<const f32x2*>(&w1S[hB * 64 + o0]);
      f32x2 vA0 = {0.f, 0.f}, vA1 = {0.f, 0.f}, vB0 = {0.f, 0.f}, vB1 = {0.f, 0.f};
#pragma unroll
      for (int u = 0; u < 8; ++u) {
        const f32x2 a = wA[u], bb2 = wB[u];
        vA0 = FMA2(accz2[0][u], a, vA0);
        vA1 = FMA2(accz2[1][u], a, vA1);
        vB0 = FMA2(accz2[0][u], bb2, vB0);
        vB1 = FMA2(accz2[1][u], bb2, vB1);
      }
      float pA0 = vA0[0] + vA0[1], pA1 = vA1[0] + vA1[1];
      float pB0 = vB0[0] + vB0[1], pB1 = vB1[0] + vB1[1];
      pA0 += __shfl_xor(pA0, 1, 64); pA0 += __shfl_xor(pA0, 2, 64);
      pA1 += __shfl_xor(pA1, 1, 64); pA1 += __shfl_xor(pA1, 2, 64);
      pB0 += __shfl_xor(pB0, 1, 64); pB0 += __shfl_xor(pB0, 2, 64);
      pB1 += __shfl_xor(pB1, 1, 64); pB1 += __shfl_xor(pB1, 2, 64);
      const int hm = hA + (q & 1);                 // my h
      const float pSelA = (q >> 1) ? pA1 : pA0;    // my row, h=hA
      const float pSelB = (q >> 1) ? pB1 : pB0;    // my row, h=hB
      const float pm = (q & 1) ? pSelB : pSelA;
      const float ex = __expf(2.f * (pm + b1S[hm]));
      sacc += w2S[hm] * (1.f - 2.f / (ex + 1.f));  // w2[hm]*tanh(pm+b1[hm])
    }
    // combine the two parity halves: lanes {q=0,1} -> row s=0; {2,3} -> s=1
    sacc += __shfl_xor(sacc, 1, 64);
    const int gbase = lane & 60;
    float sc[2];
    sc[0] = __shfl(sacc, gbase + 0, 64);
    sc[1] = __shfl(sacc, gbase + 2, 64);

    // ---- online softmax accumulate (per row, packed)
#pragma unroll
    for (int s = 0; s < 2; ++s) {
      const float nm = fmaxf(mrun[s], sc[s]);
      const float f = __expf(mrun[s] - nm), e = __expf(sc[s] - nm);
      denom[s] = denom[s] * f + e;
      const f32x2 fv = {f, f}, ev = {e, e};
#pragma unroll
      for (int u = 0; u < 8; ++u)
        oacc2[s][u] = FMA2(oacc2[s][u], fv, ev * accz2[s][u]);
      mrun[s] = nm;
    }
  }

  // ---- store (f32x2: row base 62 floats -> 8B aligned)
#pragma unroll
  for (int s = 0; s < 2; ++s) {
    const int r = row0 + 16 * s;
    if (r < NC) {
      const float inv = 1.f / denom[s];
      const f32x2 invv = {inv, inv};
      float* rowp = outp + (size_t)b * (NC * NC) + r * NC + o0;
      const int ne = (q < 3) ? 8 : 7;   // cols 48..61 for q==3
#pragma unroll
      for (int e = 0; e < 8; ++e)
        if (e < ne)
          *reinterpret_cast<f32x2*>(rowp + 2 * e) = oacc2[s][e] * invv;
    }
  }
}

// =====================================================================
// Kernel C: Chebyshev GCN (both adjacencies, shared de@gc_w), feature,
// and the 992->62 FC. wnorm == 1 exactly; relu((h+e)/2) no-op on relu'd h,e.
// =====================================================================
__global__ __launch_bounds__(256) void k_cheb_fc(
    const float* __restrict__ de, const float* __restrict__ hidden,
    const float* __restrict__ essential, const float* __restrict__ gc_w,
    const float* __restrict__ gc_b, const float* __restrict__ fc_w,
    const float* __restrict__ fc_b, float* __restrict__ zmat) {
  const int b = blockIdx.x;
  __shared__ float hidS[NC * NC], essS[NC * NC];
  __shared__ float t0S[NC * NOUT], t1S[NC * NOUT];
  __shared__ float featS[NC * NOUT];
  __shared__ float deS[NC * NBAND];
  __shared__ float red2[256];
  const int tid = threadIdx.x;

  for (int t = tid; t < NC * NBAND; t += 256) deS[t] = de[b * NC * NBAND + t];
  for (int t = tid; t < NC * NC; t += 256) {
    hidS[t] = hidden[b * NC * NC + t];
    essS[t] = essential[b * NC * NC + t];
  }
  __syncthreads();
  for (int t = tid; t < NC * NOUT; t += 256) {
    const int i = t / NOUT, f = t % NOUT;
    float a0 = gc_b[f];
    float a1 = 0.f;
#pragma unroll
    for (int qq = 0; qq < NBAND; ++qq) {
      const float d = deS[i * NBAND + qq];
      a0 += d * gc_w[qq * NOUT + f];
      a1 += d * gc_w[(NBAND + qq) * NOUT + f];
    }
    t0S[t] = a0;
    t1S[t] = a1;
  }
  __syncthreads();
  for (int t = tid; t < NC * NOUT; t += 256) {
    const int i = t / NOUT, f = t % NOUT;
    float sh = 0.f, se = 0.f;
    for (int jj = 0; jj < NC; ++jj) {
      const float t1 = t1S[jj * NOUT + f];
      sh += hidS[i * NC + jj] * t1;
      se += essS[i * NC + jj] * t1;
    }
    const float gb1 = gc_b[NOUT + f];
    const float h = fmaxf(t0S[t] + sh + gb1, 0.f);
    const float e = fmaxf(t0S[t] + se + gb1, 0.f);
    featS[t] = 0.5f * (h + e);
  }
  __syncthreads();
  {
    const int n = tid >> 2, qq = tid & 3;
    float p = 0.f;
    if (n < NC) {
      const float* fw = fc_w + n * (NC * NOUT) + qq * 248;
      const float* fs = featS + qq * 248;
      for (int m = 0; m < 248; ++m) p += fs[m] * fw[m];
    }
    red2[tid] = p;
    __syncthreads();
    if (tid < NC) {
      const float z = red2[tid * 4] + red2[tid * 4 + 1] + red2[tid * 4 + 2] + red2[tid * 4 + 3] + fc_b[tid];
      zmat[b * NC + tid] = z;
    }
  }
}

// =====================================================================
// Kernel D1: batch-norm statistics (training-mode batch stats, ddof=0).
// =====================================================================
__global__ __launch_bounds__(256) void k_bnstats(
    const float* __restrict__ zmat, const float* __restrict__ bn_g,
    const float* __restrict__ bn_b, float* __restrict__ bnp) {
  const int n = blockIdx.x;
  __shared__ float rs[256], rq[256];
  const int tid = threadIdx.x;
  float s = 0.f, sq = 0.f;
  for (int r = tid; r < NB; r += 256) {
    const float v = zmat[r * NC + n];
    s += v;
    sq += v * v;
  }
  rs[tid] = s; rq[tid] = sq;
  __syncthreads();
  for (int st = 128; st > 0; st >>= 1) {
    if (tid < st) { rs[tid] += rs[tid + st]; rq[tid] += rq[tid + st]; }
    __syncthreads();
  }
  if (tid == 0) {
    const float mean = rs[0] * (1.f / NB);
    const float var = rq[0] * (1.f / NB) - mean * mean;
    const float sc = bn_g[n] * rsqrtf(var + 1e-5f);
    bnp[2 * n] = sc;
    bnp[2 * n + 1] = bn_b[n] - mean * sc;
  }
}

// =====================================================================
// Kernel D2: apply BN + sigmoid -> output1; 62->2 FC -> output.
// =====================================================================
__global__ __launch_bounds__(64) void k_bn_out(
    const float* __restrict__ zmat, const float* __restrict__ bnp,
    const float* __restrict__ fc4_w, const float* __restrict__ fc4_b,
    float* __restrict__ out) {
  const int b = blockIdx.x;
  const int lane = threadIdx.x;
  float o1 = 0.f;
  if (lane < NC) {
    float z = zmat[b * NC + lane];
    z = z * bnp[2 * lane] + bnp[2 * lane + 1];
    o1 = 1.f / (1.f + __expf(-z));
    out[b * NC + lane] = o1;
  }
  float p0 = (lane < NC) ? o1 * fc4_w[lane] : 0.f;
  float p1 = (lane < NC) ? o1 * fc4_w[NC + lane] : 0.f;
#pragma unroll
  for (int off = 32; off > 0; off >>= 1) {
    p0 += __shfl_down(p0, off, 64);
    p1 += __shfl_down(p1, off, 64);
  }
  if (lane == 0) {
    out[NB * NC + b * 2 + 0] = p0 + fc4_b[0];
    out[NB * NC + b * 2 + 1] = p1 + fc4_b[1];
  }
}

extern "C" void kernel_launch(void* const* d_in, const int* in_sizes, int n_in,
                              void* d_out, int out_size, void* d_ws, size_t ws_size,
                              hipStream_t stream) {
  const float* de      = (const float*)d_in[0];
  const float* pcc     = (const float*)d_in[1];
  const float* Aadj    = (const float*)d_in[2];
  // d_in[3] conv_w, d_in[4] conv_b: dead (gate cancels in trace-normalized SPD)
  const float* hconv_w = (const float*)d_in[5];
  const float* hconv_b = (const float*)d_in[6];
  const float* hlin_w  = (const float*)d_in[7];
  const float* hlin_b  = (const float*)d_in[8];
  const float* econv_w = (const float*)d_in[9];
  const float* econv_b = (const float*)d_in[10];
  const float* elin_w  = (const float*)d_in[11];
  const float* elin_b  = (const float*)d_in[12];
  const float* att_w1  = (const float*)d_in[13];
  const float* att_b1  = (const float*)d_in[14];
  const float* att_w2  = (const float*)d_in[15];
  const float* gc_w    = (const float*)d_in[16];
  const float* gc_b    = (const float*)d_in[17];
  // d_in[18] wpar: wnorm = exp(w)/exp(w) = 1 exactly for 1-element wpar
  const float* fc_w    = (const float*)d_in[19];
  const float* fc_b    = (const float*)d_in[20];
  const float* bn_g    = (const float*)d_in[21];
  const float* bn_b    = (const float*)d_in[22];
  const float* fc4_w   = (const float*)d_in[23];
  const float* fc4_b   = (const float*)d_in[24];

  float* ws        = (float*)d_ws;
  float* com       = ws;                                 // 19,681,280
  float* hidden    = com + (size_t)NB * NBAND * NC * NC; //  3,936,256
  float* essential = hidden + (size_t)NB * NC * NC;      //  3,936,256
  float* zmat      = essential + (size_t)NB * NC * NC;   //     63,488
  float* bnp       = zmat + (size_t)NB * NC;             //        128
  float* lwT       = bnp + 128;                          //      7,936 (2 x 62 x 64, zero-padded)
  float* rsumG     = lwT + 2 * NC * 64;                  //        128
  // total ~111 MB of workspace

  k_spd<<<NB * NBAND, 256, 0, stream>>>(pcc, Aadj, hlin_w, elin_w, com, lwT, rsumG);
  k_branch<<<NB * 2, 128, 0, stream>>>(com, lwT, rsumG,
      hconv_w, hconv_b, hlin_b,
      econv_w, econv_b, elin_b,
      att_w1, att_b1, att_w2, hidden, essential);
  k_cheb_fc<<<NB, 256, 0, stream>>>(de, hidden, essential, gc_w, gc_b, fc_w, fc_b, zmat);
  k_bnstats<<<NC, 256, 0, stream>>>(zmat, bn_g, bn_b, bnp);
  k_bn_out<<<NB, 64, 0, stream>>>(zmat, bnp, fc4_w, fc4_b, (float*)d_out);
}

// Round 8
// 249.023 us; speedup vs baseline: 1.4499x; 1.0721x over previous
//
#include <hip/hip_runtime.h>
#include <math.h>

#define NB    1024
#define NC    62
#define NBAND 5
#define NOUT  16
#define NHID  10
#define XSTR  68   // Xc row stride (mult of 4 for float4; 68%32=4 keeps conflicts 2-way)
#define CHSTR 68   // comHS row stride in halves (136B rows; banks rq*34%32=2rq -> free 2-way)

typedef __attribute__((ext_vector_type(2))) float f32x2;
typedef __attribute__((ext_vector_type(2))) _Float16 f16x2;
typedef __attribute__((ext_vector_type(4))) _Float16 f16x4;
#define FMA2(a, b, c) __builtin_elementwise_fma((a), (b), (c))

// =====================================================================
// Kernel A: gate-cancelled SPD.
//   relu(softmax(s)*x) = g*relu(x); cov/trace cancels g^2 and 1/(c-1):
//   com[b,k] = 0.5*(N(relu(pcc_t)) + N(relu(A))) + 1e-5*I.
// f32 SYRK (v7), but OUTPUT stored as f16 comH[bk][64][64] (zero-padded):
// com is consumed only by k_branch's dot2 GEMM and f16 input rounding is
// ~5e-4 relative on ~0.05-magnitude sigmoid args -> negligible.
// Block 0 epilogue also emits lwTH (f16 c-pair-interleaved) + rsumG.
// =====================================================================
__global__ __launch_bounds__(256) void k_spd(
    const float* __restrict__ pcc, const float* __restrict__ Aadj,
    const float* __restrict__ hlin_w, const float* __restrict__ elin_w,
    _Float16* __restrict__ comH, unsigned int* __restrict__ lwTHg,
    float* __restrict__ rsumG) {
  const int bk = (blockIdx.x & 7) * 640 + (blockIdx.x >> 3);  // XCD swizzle, 5120%8==0
  const int b = bk / NBAND, k = bk % NBAND;
  __shared__ __align__(16) float Xc[NC * XSTR];
  __shared__ float red4[4];
  const int tid = threadIdx.x;
  const int j = tid >> 2, q = tid & 3, o0 = q * 16;
  const int wave = tid >> 6, lane = tid & 63;
  const bool act = (j < NC);

  float ld[16];

  // ---- src0 = relu(pcc[b,:,:,k]) : row-per-group load
#pragma unroll
  for (int u = 0; u < 16; ++u) ld[u] = 0.f;
  if (act) {
    const float* src = pcc + ((size_t)(b * NC + j) * NC + o0) * NBAND + k;
#pragma unroll
    for (int u = 0; u < 16; ++u)
      if (o0 + u < NC) ld[u] = fmaxf(src[u * NBAND], 0.f);
  }
  float rs = 0.f;
#pragma unroll
  for (int u = 0; u < 16; ++u) rs += ld[u];
  rs += __shfl_xor(rs, 1, 64);
  rs += __shfl_xor(rs, 2, 64);
  const float m0 = rs * (1.f / NC);
  float sq = 0.f;
  if (act) {
#pragma unroll
    for (int u = 0; u < 16; ++u) {
      const float cv = (o0 + u < NC) ? (ld[u] - m0) : 0.f;
      Xc[j * XSTR + o0 + u] = cv;
      sq += cv * cv;
    }
  }
#pragma unroll
  for (int off = 1; off < 64; off <<= 1) sq += __shfl_xor(sq, off, 64);
  if (lane == 0) red4[wave] = sq;

  // prefetch src1 = Aadj[b,k] rows into regs (lands under SYRK0)
#pragma unroll
  for (int u = 0; u < 16; ++u) ld[u] = 0.f;
  if (act) {
    const float* src = Aadj + ((size_t)(b * NBAND + k) * NC + j) * NC + o0;
#pragma unroll
    for (int u = 0; u < 16; ++u)
      if (o0 + u < NC) ld[u] = src[u];
  }
  __syncthreads();   // (1) Xc0 + red4 ready

  // ---- SYRK0 with 4x4 tiles (packed): G[4*tj+jj][4*tl+e]
  const int tj = tid >> 4, tl = tid & 15;
  f32x2 acc0p[8], acc1p[8];
#pragma unroll
  for (int u = 0; u < 8; ++u) acc0p[u] = (f32x2){0.f, 0.f};
  for (int i = 0; i < NC; ++i) {
    const float4 wjv = *reinterpret_cast<const float4*>(&Xc[i * XSTR + 4 * tj]);
    const float4 wlv = *reinterpret_cast<const float4*>(&Xc[i * XSTR + 4 * tl]);
    const f32x2 wl01 = {wlv.x, wlv.y}, wl23 = {wlv.z, wlv.w};
    const float wj4[4] = {wjv.x, wjv.y, wjv.z, wjv.w};
#pragma unroll
    for (int jj = 0; jj < 4; ++jj) {
      const f32x2 s = {wj4[jj], wj4[jj]};
      acc0p[jj * 2 + 0] = FMA2(s, wl01, acc0p[jj * 2 + 0]);
      acc0p[jj * 2 + 1] = FMA2(s, wl23, acc0p[jj * 2 + 1]);
    }
  }
  const float tra0 = red4[0] + red4[1] + red4[2] + red4[3];  // read BEFORE barrier (2)
  __syncthreads();   // (2) SYRK0 reads done; Xc/red4 reusable

  // ---- src1: relu + center in regs, write Xc
#pragma unroll
  for (int u = 0; u < 16; ++u) ld[u] = fmaxf(ld[u], 0.f);
  rs = 0.f;
#pragma unroll
  for (int u = 0; u < 16; ++u) rs += ld[u];
  rs += __shfl_xor(rs, 1, 64);
  rs += __shfl_xor(rs, 2, 64);
  const float m1 = rs * (1.f / NC);
  sq = 0.f;
  if (act) {
#pragma unroll
    for (int u = 0; u < 16; ++u) {
      const float cv = (o0 + u < NC) ? (ld[u] - m1) : 0.f;
      Xc[j * XSTR + o0 + u] = cv;
      sq += cv * cv;
    }
  }
#pragma unroll
  for (int off = 1; off < 64; off <<= 1) sq += __shfl_xor(sq, off, 64);
  if (lane == 0) red4[wave] = sq;
  __syncthreads();   // (3) Xc1 + red4 ready

#pragma unroll
  for (int u = 0; u < 8; ++u) acc1p[u] = (f32x2){0.f, 0.f};
  for (int i = 0; i < NC; ++i) {
    const float4 wjv = *reinterpret_cast<const float4*>(&Xc[i * XSTR + 4 * tj]);
    const float4 wlv = *reinterpret_cast<const float4*>(&Xc[i * XSTR + 4 * tl]);
    const f32x2 wl01 = {wlv.x, wlv.y}, wl23 = {wlv.z, wlv.w};
    const float wj4[4] = {wjv.x, wjv.y, wjv.z, wjv.w};
#pragma unroll
    for (int jj = 0; jj < 4; ++jj) {
      const f32x2 s = {wj4[jj], wj4[jj]};
      acc1p[jj * 2 + 0] = FMA2(s, wl01, acc1p[jj * 2 + 0]);
      acc1p[jj * 2 + 1] = FMA2(s, wl23, acc1p[jj * 2 + 1]);
    }
  }
  const float tra1 = red4[0] + red4[1] + red4[2] + red4[3];

  // ---- combine + store f16 (full 64x64 coverage incl. zero pads)
  {
    const float s0 = 0.5f / tra0, s1 = 0.5f / tra1;
    const f32x2 s0v = {s0, s0}, s1v = {s1, s1};
#pragma unroll
    for (int jj = 0; jj < 4; ++jj) {
      const int r = 4 * tj + jj;
      f32x2 v01 = FMA2(acc1p[jj * 2 + 0], s1v, acc0p[jj * 2 + 0] * s0v);
      f32x2 v23 = FMA2(acc1p[jj * 2 + 1], s1v, acc0p[jj * 2 + 1] * s0v);
      if (tj == tl) {   // diagonal element e == jj
        if (jj == 0) v01[0] += 1e-5f;
        if (jj == 1) v01[1] += 1e-5f;
        if (jj == 2) v23[0] += 1e-5f;
        if (jj == 3) v23[1] += 1e-5f;
      }
      float e0 = v01[0], e1 = v01[1], e2 = v23[0], e3 = v23[1];
      const int c0 = 4 * tl;
      if (r >= NC) { e0 = e1 = e2 = e3 = 0.f; }
      if (c0 + 2 >= NC) e2 = 0.f;   // col 62
      if (c0 + 3 >= NC) e3 = 0.f;   // col 63
      const f16x4 pk = {(_Float16)e0, (_Float16)e1, (_Float16)e2, (_Float16)e3};
      *reinterpret_cast<f16x4*>(comH + (size_t)bk * 4096 + r * 64 + c0) = pk;
    }
  }

  // ---- block 0 epilogue: f16 pair-interleaved lwTH[br][cp][o] + row sums
  if (blockIdx.x == 0) {
    for (int t = tid; t < 2 * 32 * 64; t += 256) {
      const int brx = t >> 11, rem = t & 2047, cp = rem >> 6, o = rem & 63;
      const float* lwsrc = brx ? elin_w : hlin_w;
      _Float16 lo = (_Float16)0.f, hi = (_Float16)0.f;
      if (o < NC) {
        const int c0 = 2 * cp;
        if (c0 < NC)     lo = (_Float16)lwsrc[o * NC + c0];
        if (c0 + 1 < NC) hi = (_Float16)lwsrc[o * NC + c0 + 1];
      }
      const f16x2 v = {lo, hi};
      lwTHg[t] = __builtin_bit_cast(unsigned int, v);
    }
    if (tid < 64) {
      float sh = 0.f, se = 0.f;
      if (tid < NC) {
        for (int c = 0; c < NC; ++c) { sh += hlin_w[tid * NC + c]; se += elin_w[tid * NC + c]; }
      }
      rsumG[tid] = sh;
      rsumG[64 + tid] = se;
    }
  }
}

// =====================================================================
// Kernel B (v8): f16 dot2 GEMM. 2-wave blocks; thread (rq,q) owns rows
// {row0,row0+16} x cols o0..o0+15. Whole band (8KB f16) double-buffered;
// T14 staging (issue before GEMM, ds_write after, ONE barrier per band).
// Per c-pair: 2 b32 (com half2) + 4 b128 (16 lw half2) + 32 v_dot2 ->
// LDS bytes and VALU both halved vs the f32 path.
// =====================================================================
__global__ __launch_bounds__(128, 2) void k_branch(
    const _Float16* __restrict__ comH, const unsigned int* __restrict__ lwTHg,
    const float* __restrict__ rsumG,
    const float* __restrict__ hconv_w, const float* __restrict__ hconv_b,
    const float* __restrict__ hlin_b,
    const float* __restrict__ econv_w, const float* __restrict__ econv_b,
    const float* __restrict__ elin_b,
    const float* __restrict__ att_w1,  const float* __restrict__ att_b1,
    const float* __restrict__ att_w2,
    float* __restrict__ hiddenO, float* __restrict__ essentialO) {
  const int bid = (blockIdx.x & 7) * 256 + (blockIdx.x >> 3);  // XCD swizzle
  const int b = bid >> 1, br = bid & 1;

  const float* __restrict__ cw = br ? econv_w : hconv_w;
  const float* __restrict__ cb = br ? econv_b : hconv_b;
  const float* __restrict__ lb = br ? elin_b : hlin_b;
  float* __restrict__ outp = br ? essentialO : hiddenO;

  __shared__ __align__(16) _Float16 comHS[2][64 * CHSTR];  // 17408 B dbuf
  __shared__ __align__(16) unsigned int lwS[32 * 64];      // 8192 B [cp][o] half2
  __shared__ __align__(8)  float w1S[NHID * 64];           // [h][o], zero-padded
  __shared__ __align__(8)  float rsumS[64], lbS[64];
  __shared__ float b1S[16], w2S[16], cwS[8], cbS[8];

  const int tid = threadIdx.x;             // 0..127
  const int w = tid >> 6, lane = tid & 63;
  const int rq = lane >> 2, q = lane & 3, o0 = q * 16;
  const int row0 = w * 32 + rq;            // thread rows: row0, row0+16

  // ---- LDS fills
  {
    const uint4* src = reinterpret_cast<const uint4*>(lwTHg + br * 2048);
    uint4* dst = reinterpret_cast<uint4*>(lwS);
#pragma unroll
    for (int i = 0; i < 4; ++i) dst[tid + i * 128] = src[tid + i * 128];  // 512 uint4
  }
  for (int t = tid; t < NHID * 64; t += 128) {
    const int c = t & 63;
    w1S[t] = (c < NC) ? att_w1[(t >> 6) * NC + c] : 0.f;
  }
  if (tid < 64) {
    rsumS[tid] = rsumG[br * 64 + tid];
    lbS[tid] = (tid < NC) ? lb[tid] : 0.f;
  }
  if (tid < NHID) { b1S[tid] = att_b1[tid]; w2S[tid] = att_w2[tid]; }
  if (tid < NBAND) { cwS[tid] = cw[tid]; cbS[tid] = cb[tid]; }

  // band staging: 8KB = 512 float4; thread t: idx = i*128+t, row=idx>>3, ch=idx&7
  const float4* gsrc = reinterpret_cast<const float4*>(comH + (size_t)(b * NBAND) * 4096);
  float4 pf[4];
  auto stage_issue = [&](int band) {
    const float4* s = gsrc + band * 512;
#pragma unroll
    for (int i = 0; i < 4; ++i) pf[i] = s[i * 128 + tid];
  };
  auto stage_write = [&](_Float16* buf) {
#pragma unroll
    for (int i = 0; i < 4; ++i) {
      const int idx = i * 128 + tid;
      const int row = idx >> 3, ch = idx & 7;
      float2* p = reinterpret_cast<float2*>(buf + row * CHSTR + ch * 8);  // 8B aligned
      p[0] = make_float2(pf[i].x, pf[i].y);
      p[1] = make_float2(pf[i].z, pf[i].w);
    }
  };

  stage_issue(0);
  stage_write(comHS[0]);
  __syncthreads();

  f32x2 oacc2[2][8];
#pragma unroll
  for (int s = 0; s < 2; ++s)
#pragma unroll
    for (int u = 0; u < 8; ++u) oacc2[s][u] = (f32x2){0.f, 0.f};
  float denom[2] = {0.f, 0.f};
  float mrun[2] = {-1e30f, -1e30f};

  f32x2 accz2[2][8];

#pragma unroll 1
  for (int kb = 0; kb < NBAND; ++kb) {
#pragma unroll
    for (int s = 0; s < 2; ++s)
#pragma unroll
      for (int u = 0; u < 8; ++u) accz2[s][u] = (f32x2){0.f, 0.f};

    if (kb < NBAND - 1) stage_issue(kb + 1);   // T14: issue early

    // ---- dot2 GEMM over 32 c-pairs
    {
      const _Float16* cbuf = comHS[kb & 1];
      const uint4* lw4 = reinterpret_cast<const uint4*>(lwS);
#pragma unroll 4
      for (int cp = 0; cp < 32; ++cp) {
        const f16x2 a0 = *reinterpret_cast<const f16x2*>(cbuf + row0 * CHSTR + 2 * cp);
        const f16x2 a1 = *reinterpret_cast<const f16x2*>(cbuf + (row0 + 16) * CHSTR + 2 * cp);
        const uint4 wA = lw4[cp * 16 + 4 * q + 0];
        const uint4 wB = lw4[cp * 16 + 4 * q + 1];
        const uint4 wC = lw4[cp * 16 + 4 * q + 2];
        const uint4 wD = lw4[cp * 16 + 4 * q + 3];
        const unsigned int wu[16] = {wA.x, wA.y, wA.z, wA.w, wB.x, wB.y, wB.z, wB.w,
                                     wC.x, wC.y, wC.z, wC.w, wD.x, wD.y, wD.z, wD.w};
#pragma unroll
        for (int u = 0; u < 16; ++u) {
          const f16x2 wh = __builtin_bit_cast(f16x2, wu[u]);
          accz2[0][u >> 1][u & 1] =
              __builtin_amdgcn_fdot2(a0, wh, accz2[0][u >> 1][u & 1], false);
          accz2[1][u >> 1][u & 1] =
              __builtin_amdgcn_fdot2(a1, wh, accz2[1][u >> 1][u & 1], false);
        }
      }
    }

    if (kb < NBAND - 1) stage_write(comHS[(kb + 1) & 1]);   // T14: write late

    // ---- sigmoid in place -> z (packed pre-activation)
    {
      const float ck = cwS[kb], dk = cbS[kb];
      const f32x2 ckv = {ck, ck}, dkv = {dk, dk};
      const f32x2* rs2 = reinterpret_cast<const f32x2*>(&rsumS[o0]);
      const f32x2* lb2 = reinterpret_cast<const f32x2*>(&lbS[o0]);
      f32x2 basev[8];
#pragma unroll
      for (int u = 0; u < 8; ++u) basev[u] = FMA2(dkv, rs2[u], lb2[u]);
#pragma unroll
      for (int s = 0; s < 2; ++s)
#pragma unroll
        for (int u = 0; u < 8; ++u) {
          const f32x2 zv = FMA2(ckv, accz2[s][u], basev[u]);
          accz2[s][u][0] = 1.f / (1.f + __expf(-zv[0]));
          accz2[s][u][1] = 1.f / (1.f + __expf(-zv[1]));
        }
    }

    // ---- scorer: paired-h parity trick (packed partials)
    float sacc = 0.f;
#pragma unroll
    for (int t = 0; t < 5; ++t) {
      const int hA = 2 * t, hB = 2 * t + 1;
      const f32x2* wA2 = reinterpret_cast<const f32x2*>(&w1S[hA * 64 + o0]);
      const f32x2* wB2 = reinterpret_cast<const f32x2*>(&w1S[hB * 64 + o0]);
      f32x2 vA0 = {0.f, 0.f}, vA1 = {0.f, 0.f}, vB0 = {0.f, 0.f}, vB1 = {0.f, 0.f};
#pragma unroll
      for (int u = 0; u < 8; ++u) {
        const f32x2 a = wA2[u], bb2 = wB2[u];
        vA0 = FMA2(accz2[0][u], a, vA0);
        vA1 = FMA2(accz2[1][u], a, vA1);
        vB0 = FMA2(accz2[0][u], bb2, vB0);
        vB1 = FMA2(accz2[1][u], bb2, vB1);
      }
      float pA0 = vA0[0] + vA0[1], pA1 = vA1[0] + vA1[1];
      float pB0 = vB0[0] + vB0[1], pB1 = vB1[0] + vB1[1];
      pA0 += __shfl_xor(pA0, 1, 64); pA0 += __shfl_xor(pA0, 2, 64);
      pA1 += __shfl_xor(pA1, 1, 64); pA1 += __shfl_xor(pA1, 2, 64);
      pB0 += __shfl_xor(pB0, 1, 64); pB0 += __shfl_xor(pB0, 2, 64);
      pB1 += __shfl_xor(pB1, 1, 64); pB1 += __shfl_xor(pB1, 2, 64);
      const int hm = hA + (q & 1);                 // my h
      const float pSelA = (q >> 1) ? pA1 : pA0;    // my row, h=hA
      const float pSelB = (q >> 1) ? pB1 : pB0;    // my row, h=hB
      const float pm = (q & 1) ? pSelB : pSelA;
      const float ex = __expf(2.f * (pm + b1S[hm]));
      sacc += w2S[hm] * (1.f - 2.f / (ex + 1.f));  // w2[hm]*tanh(pm+b1[hm])
    }
    sacc += __shfl_xor(sacc, 1, 64);
    const int gbase = lane & 60;
    float sc[2];
    sc[0] = __shfl(sacc, gbase + 0, 64);
    sc[1] = __shfl(sacc, gbase + 2, 64);

    // ---- online softmax accumulate (per row, packed)
#pragma unroll
    for (int s = 0; s < 2; ++s) {
      const float nm = fmaxf(mrun[s], sc[s]);
      const float f = __expf(mrun[s] - nm), e = __expf(sc[s] - nm);
      denom[s] = denom[s] * f + e;
      const f32x2 fv = {f, f}, ev = {e, e};
#pragma unroll
      for (int u = 0; u < 8; ++u)
        oacc2[s][u] = FMA2(oacc2[s][u], fv, ev * accz2[s][u]);
      mrun[s] = nm;
    }

    __syncthreads();   // next buffer staged & this buffer's reads complete
  }

  // ---- store (f32x2: row base 62 floats -> 8B aligned)
#pragma unroll
  for (int s = 0; s < 2; ++s) {
    const int r = row0 + 16 * s;
    if (r < NC) {
      const float inv = 1.f / denom[s];
      const f32x2 invv = {inv, inv};
      float* rowp = outp + (size_t)b * (NC * NC) + r * NC + o0;
      const int ne = (q < 3) ? 8 : 7;   // cols 48..61 for q==3
#pragma unroll
      for (int e = 0; e < 8; ++e)
        if (e < ne)
          *reinterpret_cast<f32x2*>(rowp + 2 * e) = oacc2[s][e] * invv;
    }
  }
}

// =====================================================================
// Kernel C: Chebyshev GCN (both adjacencies, shared de@gc_w), feature,
// and the 992->62 FC. wnorm == 1 exactly; relu((h+e)/2) no-op on relu'd h,e.
// =====================================================================
__global__ __launch_bounds__(256) void k_cheb_fc(
    const float* __restrict__ de, const float* __restrict__ hidden,
    const float* __restrict__ essential, const float* __restrict__ gc_w,
    const float* __restrict__ gc_b, const float* __restrict__ fc_w,
    const float* __restrict__ fc_b, float* __restrict__ zmat) {
  const int b = blockIdx.x;
  __shared__ float hidS[NC * NC], essS[NC * NC];
  __shared__ float t0S[NC * NOUT], t1S[NC * NOUT];
  __shared__ float featS[NC * NOUT];
  __shared__ float deS[NC * NBAND];
  __shared__ float red2[256];
  const int tid = threadIdx.x;

  for (int t = tid; t < NC * NBAND; t += 256) deS[t] = de[b * NC * NBAND + t];
  for (int t = tid; t < NC * NC; t += 256) {
    hidS[t] = hidden[b * NC * NC + t];
    essS[t] = essential[b * NC * NC + t];
  }
  __syncthreads();
  for (int t = tid; t < NC * NOUT; t += 256) {
    const int i = t / NOUT, f = t % NOUT;
    float a0 = gc_b[f];
    float a1 = 0.f;
#pragma unroll
    for (int qq = 0; qq < NBAND; ++qq) {
      const float d = deS[i * NBAND + qq];
      a0 += d * gc_w[qq * NOUT + f];
      a1 += d * gc_w[(NBAND + qq) * NOUT + f];
    }
    t0S[t] = a0;
    t1S[t] = a1;
  }
  __syncthreads();
  for (int t = tid; t < NC * NOUT; t += 256) {
    const int i = t / NOUT, f = t % NOUT;
    float sh = 0.f, se = 0.f;
    for (int jj = 0; jj < NC; ++jj) {
      const float t1 = t1S[jj * NOUT + f];
      sh += hidS[i * NC + jj] * t1;
      se += essS[i * NC + jj] * t1;
    }
    const float gb1 = gc_b[NOUT + f];
    const float h = fmaxf(t0S[t] + sh + gb1, 0.f);
    const float e = fmaxf(t0S[t] + se + gb1, 0.f);
    featS[t] = 0.5f * (h + e);
  }
  __syncthreads();
  {
    const int n = tid >> 2, qq = tid & 3;
    float p = 0.f;
    if (n < NC) {
      const float* fw = fc_w + n * (NC * NOUT) + qq * 248;
      const float* fs = featS + qq * 248;
      for (int m = 0; m < 248; ++m) p += fs[m] * fw[m];
    }
    red2[tid] = p;
    __syncthreads();
    if (tid < NC) {
      const float z = red2[tid * 4] + red2[tid * 4 + 1] + red2[tid * 4 + 2] + red2[tid * 4 + 3] + fc_b[tid];
      zmat[b * NC + tid] = z;
    }
  }
}

// =====================================================================
// Kernel D1: batch-norm statistics (training-mode batch stats, ddof=0).
// =====================================================================
__global__ __launch_bounds__(256) void k_bnstats(
    const float* __restrict__ zmat, const float* __restrict__ bn_g,
    const float* __restrict__ bn_b, float* __restrict__ bnp) {
  const int n = blockIdx.x;
  __shared__ float rs[256], rq[256];
  const int tid = threadIdx.x;
  float s = 0.f, sq = 0.f;
  for (int r = tid; r < NB; r += 256) {
    const float v = zmat[r * NC + n];
    s += v;
    sq += v * v;
  }
  rs[tid] = s; rq[tid] = sq;
  __syncthreads();
  for (int st = 128; st > 0; st >>= 1) {
    if (tid < st) { rs[tid] += rs[tid + st]; rq[tid] += rq[tid + st]; }
    __syncthreads();
  }
  if (tid == 0) {
    const float mean = rs[0] * (1.f / NB);
    const float var = rq[0] * (1.f / NB) - mean * mean;
    const float sc = bn_g[n] * rsqrtf(var + 1e-5f);
    bnp[2 * n] = sc;
    bnp[2 * n + 1] = bn_b[n] - mean * sc;
  }
}

// =====================================================================
// Kernel D2: apply BN + sigmoid -> output1; 62->2 FC -> output.
// =====================================================================
__global__ __launch_bounds__(64) void k_bn_out(
    const float* __restrict__ zmat, const float* __restrict__ bnp,
    const float* __restrict__ fc4_w, const float* __restrict__ fc4_b,
    float* __restrict__ out) {
  const int b = blockIdx.x;
  const int lane = threadIdx.x;
  float o1 = 0.f;
  if (lane < NC) {
    float z = zmat[b * NC + lane];
    z = z * bnp[2 * lane] + bnp[2 * lane + 1];
    o1 = 1.f / (1.f + __expf(-z));
    out[b * NC + lane] = o1;
  }
  float p0 = (lane < NC) ? o1 * fc4_w[lane] : 0.f;
  float p1 = (lane < NC) ? o1 * fc4_w[NC + lane] : 0.f;
#pragma unroll
  for (int off = 32; off > 0; off >>= 1) {
    p0 += __shfl_down(p0, off, 64);
    p1 += __shfl_down(p1, off, 64);
  }
  if (lane == 0) {
    out[NB * NC + b * 2 + 0] = p0 + fc4_b[0];
    out[NB * NC + b * 2 + 1] = p1 + fc4_b[1];
  }
}

extern "C" void kernel_launch(void* const* d_in, const int* in_sizes, int n_in,
                              void* d_out, int out_size, void* d_ws, size_t ws_size,
                              hipStream_t stream) {
  const float* de      = (const float*)d_in[0];
  const float* pcc     = (const float*)d_in[1];
  const float* Aadj    = (const float*)d_in[2];
  // d_in[3] conv_w, d_in[4] conv_b: dead (gate cancels in trace-normalized SPD)
  const float* hconv_w = (const float*)d_in[5];
  const float* hconv_b = (const float*)d_in[6];
  const float* hlin_w  = (const float*)d_in[7];
  const float* hlin_b  = (const float*)d_in[8];
  const float* econv_w = (const float*)d_in[9];
  const float* econv_b = (const float*)d_in[10];
  const float* elin_w  = (const float*)d_in[11];
  const float* elin_b  = (const float*)d_in[12];
  const float* att_w1  = (const float*)d_in[13];
  const float* att_b1  = (const float*)d_in[14];
  const float* att_w2  = (const float*)d_in[15];
  const float* gc_w    = (const float*)d_in[16];
  const float* gc_b    = (const float*)d_in[17];
  // d_in[18] wpar: wnorm = exp(w)/exp(w) = 1 exactly for 1-element wpar
  const float* fc_w    = (const float*)d_in[19];
  const float* fc_b    = (const float*)d_in[20];
  const float* bn_g    = (const float*)d_in[21];
  const float* bn_b    = (const float*)d_in[22];
  const float* fc4_w   = (const float*)d_in[23];
  const float* fc4_b   = (const float*)d_in[24];

  float* ws        = (float*)d_ws;
  _Float16* comH   = (_Float16*)ws;                      // 5120*4096 halves = 41.9 MB
  float* hidden    = ws + 10485760;                      //  3,936,256 floats
  float* essential = hidden + (size_t)NB * NC * NC;
  float* zmat      = essential + (size_t)NB * NC * NC;   //     63,488
  float* bnp       = zmat + (size_t)NB * NC;             //        128
  unsigned int* lwTHg = (unsigned int*)(bnp + 128);      //      4,096 u32 (2 x 32 x 64 half2)
  float* rsumG     = (float*)(lwTHg + 4096);             //        128
  // total ~74 MB of workspace

  k_spd<<<NB * NBAND, 256, 0, stream>>>(pcc, Aadj, hlin_w, elin_w, comH, lwTHg, rsumG);
  k_branch<<<NB * 2, 128, 0, stream>>>(comH, lwTHg, rsumG,
      hconv_w, hconv_b, hlin_b,
      econv_w, econv_b, elin_b,
      att_w1, att_b1, att_w2, hidden, essential);
  k_cheb_fc<<<NB, 256, 0, stream>>>(de, hidden, essential, gc_w, gc_b, fc_w, fc_b, zmat);
  k_bnstats<<<NC, 256, 0, stream>>>(zmat, bn_g, bn_b, bnp);
  k_bn_out<<<NB, 64, 0, stream>>>(zmat, bnp, fc4_w, fc4_b, (float*)d_out);
}

// Round 10
// 214.108 us; speedup vs baseline: 1.6863x; 1.1631x over previous
//
#include <hip/hip_runtime.h>
#include <math.h>

#define NB    1024
#define NC    62
#define NBAND 5
#define NOUT  16
#define NHID  10
#define CW    33   // comHS row stride in u32 (66 halves; odd -> conflict-free writes/reads)

typedef __attribute__((ext_vector_type(2))) float f32x2;
typedef __attribute__((ext_vector_type(2))) _Float16 f16x2;
typedef __attribute__((ext_vector_type(4))) _Float16 f16x4;
typedef __attribute__((ext_vector_type(2))) __fp16 fp16v2;   // cvt_pkrtz result type
#define FMA2(a, b, c) __builtin_elementwise_fma((a), (b), (c))
#define DOT2(a, b, c) __builtin_amdgcn_fdot2((a), (b), (c), false)

__device__ __forceinline__ f16x2 u2h(unsigned int u) { return __builtin_bit_cast(f16x2, u); }
__device__ __forceinline__ unsigned int pk2u(float x, float y) {
  const fp16v2 v = __builtin_amdgcn_cvt_pkrtz(x, y);
  return __builtin_bit_cast(unsigned int, v);
}

// =====================================================================
// Kernel A: gate-cancelled SPD.
//   relu(softmax(s)*x) = g*relu(x); cov/trace cancels g^2 and 1/(c-1):
//   com[b,k] = 0.5*(N(relu(pcc_t)) + N(relu(A))) + 1e-5*I.
// v9: Xc stored in LDS as f16 i-PAIRS: XcIH[ip][c] = {Xc[2ip][c],Xc[2ip+1][c]}.
// SYRK reads 2 b128 per ip (= 2 i-steps) and uses fdot2 -> LDS halved vs v8.
// Load phase: thread (p = tid>>3, q8 = tid&7) owns rows {2p,2p+1} x cols
// 8q8..8q8+7; centering in regs (8-lane shuffles); trace f32.
// =====================================================================
__global__ __launch_bounds__(256) void k_spd(
    const float* __restrict__ pcc, const float* __restrict__ Aadj,
    const float* __restrict__ hlin_w, const float* __restrict__ elin_w,
    const float* __restrict__ att_w1,
    _Float16* __restrict__ comH, unsigned int* __restrict__ lwTHg,
    unsigned int* __restrict__ w1Hg, float* __restrict__ rsumG) {
  const int bk = (blockIdx.x & 7) * 640 + (blockIdx.x >> 3);  // XCD swizzle, 5120%8==0
  const int b = bk / NBAND, k = bk % NBAND;
  __shared__ __align__(16) unsigned int XcIH[31 * 64];   // 7936 B, f16x2 [ip][c]
  __shared__ float red4[4];
  const int tid = threadIdx.x;
  const int wave = tid >> 6, lane = tid & 63;
  const int p = tid >> 3, q8 = tid & 7, c0 = q8 * 8;
  const bool act = (p < 31);
  const int r0 = 2 * p, r1 = r0 + 1;

  float ld0[8], ld1[8];

  auto center_pack = [&](float (&a0)[8], float (&a1)[8]) -> void {
    // row sums across the 8 q8-lanes of this row-pair
    float s0 = 0.f, s1 = 0.f;
#pragma unroll
    for (int u = 0; u < 8; ++u) { s0 += a0[u]; s1 += a1[u]; }
    s0 += __shfl_xor(s0, 1, 64); s0 += __shfl_xor(s0, 2, 64); s0 += __shfl_xor(s0, 4, 64);
    s1 += __shfl_xor(s1, 1, 64); s1 += __shfl_xor(s1, 2, 64); s1 += __shfl_xor(s1, 4, 64);
    const float m0 = s0 * (1.f / NC), m1 = s1 * (1.f / NC);
    float sq = 0.f;
    if (act) {
      unsigned int pk[8];
#pragma unroll
      for (int u = 0; u < 8; ++u) {
        const int c = c0 + u;
        const float cv0 = (c < NC) ? (a0[u] - m0) : 0.f;
        const float cv1 = (c < NC) ? (a1[u] - m1) : 0.f;
        sq += cv0 * cv0 + cv1 * cv1;
        pk[u] = pk2u(cv0, cv1);
      }
      uint4* d = reinterpret_cast<uint4*>(XcIH + p * 64 + c0);
      d[0] = make_uint4(pk[0], pk[1], pk[2], pk[3]);
      d[1] = make_uint4(pk[4], pk[5], pk[6], pk[7]);
    }
#pragma unroll
    for (int off = 1; off < 64; off <<= 1) sq += __shfl_xor(sq, off, 64);
    if (lane == 0) red4[wave] = sq;
  };

  // ---- src0 = relu(pcc[b,:,:,k]) : stride-5 scalar loads
#pragma unroll
  for (int u = 0; u < 8; ++u) { ld0[u] = 0.f; ld1[u] = 0.f; }
  if (act) {
    const float* s0p = pcc + ((size_t)(b * NC + r0) * NC + c0) * NBAND + k;
    const float* s1p = pcc + ((size_t)(b * NC + r1) * NC + c0) * NBAND + k;
#pragma unroll
    for (int u = 0; u < 8; ++u) {
      if (c0 + u < NC) {
        ld0[u] = fmaxf(s0p[u * NBAND], 0.f);
        ld1[u] = fmaxf(s1p[u * NBAND], 0.f);
      }
    }
  }
  center_pack(ld0, ld1);

  // prefetch src1 = Aadj rows (float2: row byte-offset 248r is 8B-aligned)
#pragma unroll
  for (int u = 0; u < 8; ++u) { ld0[u] = 0.f; ld1[u] = 0.f; }
  if (act) {
    const float* a0p = Aadj + ((size_t)(b * NBAND + k) * NC + r0) * NC + c0;
    const float* a1p = Aadj + ((size_t)(b * NBAND + k) * NC + r1) * NC + c0;
#pragma unroll
    for (int e = 0; e < 4; ++e) {
      const int c = c0 + 2 * e;
      if (c + 1 < NC) {
        const float2 v0 = *reinterpret_cast<const float2*>(a0p + 2 * e);
        const float2 v1 = *reinterpret_cast<const float2*>(a1p + 2 * e);
        ld0[2 * e] = v0.x; ld0[2 * e + 1] = v0.y;
        ld1[2 * e] = v1.x; ld1[2 * e + 1] = v1.y;
      } else if (c < NC) {
        ld0[2 * e] = a0p[2 * e];
        ld1[2 * e] = a1p[2 * e];
      }
    }
  }
  __syncthreads();   // (1) XcIH(src0) + red4 ready

  // ---- SYRK0: thread (tj,tl) owns G[4tj..][4tl..]; fdot2 over i-pairs
  const int tj = tid >> 4, tl = tid & 15;
  float acc0[16], acc1[16];
#pragma unroll
  for (int u = 0; u < 16; ++u) acc0[u] = 0.f;
  for (int ip = 0; ip < 31; ++ip) {
    const uint4 ju = *reinterpret_cast<const uint4*>(XcIH + ip * 64 + 4 * tj);
    const uint4 lu = *reinterpret_cast<const uint4*>(XcIH + ip * 64 + 4 * tl);
    const unsigned int jw[4] = {ju.x, ju.y, ju.z, ju.w};
    const unsigned int lw_[4] = {lu.x, lu.y, lu.z, lu.w};
#pragma unroll
    for (int jj = 0; jj < 4; ++jj)
#pragma unroll
      for (int e = 0; e < 4; ++e)
        acc0[jj * 4 + e] = DOT2(u2h(jw[jj]), u2h(lw_[e]), acc0[jj * 4 + e]);
  }
  const float tra0 = red4[0] + red4[1] + red4[2] + red4[3];  // read BEFORE (2)
  __syncthreads();   // (2) SYRK0 reads done; XcIH/red4 reusable

  // ---- src1: relu + center + pack
#pragma unroll
  for (int u = 0; u < 8; ++u) { ld0[u] = fmaxf(ld0[u], 0.f); ld1[u] = fmaxf(ld1[u], 0.f); }
  center_pack(ld0, ld1);
  __syncthreads();   // (3) XcIH(src1) + red4 ready

#pragma unroll
  for (int u = 0; u < 16; ++u) acc1[u] = 0.f;
  for (int ip = 0; ip < 31; ++ip) {
    const uint4 ju = *reinterpret_cast<const uint4*>(XcIH + ip * 64 + 4 * tj);
    const uint4 lu = *reinterpret_cast<const uint4*>(XcIH + ip * 64 + 4 * tl);
    const unsigned int jw[4] = {ju.x, ju.y, ju.z, ju.w};
    const unsigned int lw_[4] = {lu.x, lu.y, lu.z, lu.w};
#pragma unroll
    for (int jj = 0; jj < 4; ++jj)
#pragma unroll
      for (int e = 0; e < 4; ++e)
        acc1[jj * 4 + e] = DOT2(u2h(jw[jj]), u2h(lw_[e]), acc1[jj * 4 + e]);
  }
  const float tra1 = red4[0] + red4[1] + red4[2] + red4[3];

  // ---- combine + f16 store (full 64x64 coverage incl. zero pads)
  {
    const float s0 = 0.5f / tra0, s1 = 0.5f / tra1;
#pragma unroll
    for (int jj = 0; jj < 4; ++jj) {
      const int r = 4 * tj + jj;
      float e0 = acc0[jj * 4 + 0] * s0 + acc1[jj * 4 + 0] * s1;
      float e1 = acc0[jj * 4 + 1] * s0 + acc1[jj * 4 + 1] * s1;
      float e2 = acc0[jj * 4 + 2] * s0 + acc1[jj * 4 + 2] * s1;
      float e3 = acc0[jj * 4 + 3] * s0 + acc1[jj * 4 + 3] * s1;
      if (tj == tl) {
        if (jj == 0) e0 += 1e-5f;
        if (jj == 1) e1 += 1e-5f;
        if (jj == 2) e2 += 1e-5f;
        if (jj == 3) e3 += 1e-5f;
      }
      const int c0s = 4 * tl;
      if (r >= NC) { e0 = e1 = e2 = e3 = 0.f; }
      if (c0s + 2 >= NC) e2 = 0.f;
      if (c0s + 3 >= NC) e3 = 0.f;
      uint2 pk;
      pk.x = pk2u(e0, e1);
      pk.y = pk2u(e2, e3);
      *reinterpret_cast<uint2*>(comH + (size_t)bk * 4096 + r * 64 + c0s) = pk;
    }
  }

  // ---- block 0 epilogue: lwTH (f16 c-pairs), w1H (f16 o-pairs), row sums
  if (blockIdx.x == 0) {
    for (int t = tid; t < 2 * 32 * 64; t += 256) {
      const int brx = t >> 11, rem = t & 2047, cp = rem >> 6, o = rem & 63;
      const float* lwsrc = brx ? elin_w : hlin_w;
      float lo = 0.f, hi = 0.f;
      if (o < NC) {
        const int c = 2 * cp;
        if (c < NC)     lo = lwsrc[o * NC + c];
        if (c + 1 < NC) hi = lwsrc[o * NC + c + 1];
      }
      lwTHg[t] = pk2u(lo, hi);
    }
    for (int t = tid; t < NHID * 32; t += 256) {
      const int h = t >> 5, op = t & 31;
      const float lo = (2 * op < NC) ? att_w1[h * NC + 2 * op] : 0.f;
      const float hi = (2 * op + 1 < NC) ? att_w1[h * NC + 2 * op + 1] : 0.f;
      w1Hg[t] = pk2u(lo, hi);
    }
    if (tid < 64) {
      float sh = 0.f, se = 0.f;
      if (tid < NC) {
        for (int c = 0; c < NC; ++c) { sh += hlin_w[tid * NC + c]; se += elin_w[tid * NC + c]; }
      }
      rsumG[tid] = sh;
      rsumG[64 + tid] = se;
    }
  }
}

// =====================================================================
// Kernel B (v9): T15 double-pipeline — GEMM(kb+1) issues BEFORE the
// VALU epilogue of band kb (dual parity-indexed accumulators, full
// unroll) so the LDS and VALU pipes overlap instead of alternating.
// w1 in f16 pairs (scorer via fdot2 on cvt_pkrtz'd z): 20 uint4 reads
// per band vs 80 b64. Staging: CW=33 u32 rows (odd) + b32 writes ->
// conflict-free. One barrier per band.
// =====================================================================
__global__ __launch_bounds__(128, 2) void k_branch(
    const _Float16* __restrict__ comH, const unsigned int* __restrict__ lwTHg,
    const unsigned int* __restrict__ w1Hg, const float* __restrict__ rsumG,
    const float* __restrict__ hconv_w, const float* __restrict__ hconv_b,
    const float* __restrict__ hlin_b,
    const float* __restrict__ econv_w, const float* __restrict__ econv_b,
    const float* __restrict__ elin_b,
    const float* __restrict__ att_b1,  const float* __restrict__ att_w2,
    float* __restrict__ hiddenO, float* __restrict__ essentialO) {
  const int bid = (blockIdx.x & 7) * 256 + (blockIdx.x >> 3);  // XCD swizzle
  const int b = bid >> 1, br = bid & 1;

  const float* __restrict__ cw = br ? econv_w : hconv_w;
  const float* __restrict__ cb = br ? econv_b : hconv_b;
  const float* __restrict__ lb = br ? elin_b : hlin_b;
  float* __restrict__ outp = br ? essentialO : hiddenO;

  __shared__ __align__(16) unsigned int comHS[2][64 * CW];  // 16896 B dbuf
  __shared__ __align__(16) unsigned int lwS[32 * 64];       // 8192 B [cp][o] f16x2
  __shared__ __align__(16) unsigned int w1HS[NHID * 32];    // 1280 B [h][op] f16x2
  __shared__ float rsumS[64], lbS[64];
  __shared__ float b1S[16], w2S[16], cwS[8], cbS[8];

  const int tid = threadIdx.x;             // 0..127
  const int w = tid >> 6, lane = tid & 63;
  const int rq = lane >> 2, q = lane & 3, o0 = q * 16;
  const int row0 = w * 32 + rq;            // thread rows: row0, row0+16

  // ---- LDS fills
  {
    const uint4* src = reinterpret_cast<const uint4*>(lwTHg + br * 2048);
    uint4* dst = reinterpret_cast<uint4*>(lwS);
#pragma unroll
    for (int i = 0; i < 4; ++i) dst[tid + i * 128] = src[tid + i * 128];
  }
  for (int t = tid; t < NHID * 32; t += 128) w1HS[t] = w1Hg[t];
  if (tid < 64) {
    rsumS[tid] = rsumG[br * 64 + tid];
    lbS[tid] = (tid < NC) ? lb[tid] : 0.f;
  }
  if (tid < NHID) { b1S[tid] = att_b1[tid]; w2S[tid] = att_w2[tid]; }
  if (tid < NBAND) { cwS[tid] = cw[tid]; cbS[tid] = cb[tid]; }

  // ---- staging: band = 512 float4; thread t covers idx = i*128+t
  const float4* gsrc = reinterpret_cast<const float4*>(comH + (size_t)(b * NBAND) * 4096);
  float4 pf[4];
  auto stage_issue = [&](int band) {
#pragma unroll
    for (int i = 0; i < 4; ++i) pf[i] = gsrc[band * 512 + i * 128 + tid];
  };
  auto stage_write = [&](unsigned int* buf) {
#pragma unroll
    for (int i = 0; i < 4; ++i) {
      const int idx = i * 128 + tid;
      const int row = idx >> 3, ch = idx & 7;
      unsigned int* d = buf + row * CW + ch * 4;
      d[0] = __builtin_bit_cast(unsigned int, pf[i].x);
      d[1] = __builtin_bit_cast(unsigned int, pf[i].y);
      d[2] = __builtin_bit_cast(unsigned int, pf[i].z);
      d[3] = __builtin_bit_cast(unsigned int, pf[i].w);
    }
  };

  f32x2 oacc2[2][8];
#pragma unroll
  for (int s = 0; s < 2; ++s)
#pragma unroll
    for (int u = 0; u < 8; ++u) oacc2[s][u] = (f32x2){0.f, 0.f};
  float denom[2] = {0.f, 0.f};
  float mrun[2] = {-1e30f, -1e30f};

  f32x2 accz2[2][2][8];   // [parity][row s][o-pair u]

  auto gemm = [&](const unsigned int* cbuf, f32x2 (&az)[2][8]) {
#pragma unroll
    for (int s = 0; s < 2; ++s)
#pragma unroll
      for (int u = 0; u < 8; ++u) az[s][u] = (f32x2){0.f, 0.f};
    const uint4* lw4 = reinterpret_cast<const uint4*>(lwS);
#pragma unroll 4
    for (int cp = 0; cp < 32; ++cp) {
      const f16x2 a0 = u2h(cbuf[row0 * CW + cp]);
      const f16x2 a1 = u2h(cbuf[(row0 + 16) * CW + cp]);
      const uint4 wA = lw4[cp * 16 + 4 * q + 0];
      const uint4 wB = lw4[cp * 16 + 4 * q + 1];
      const uint4 wC = lw4[cp * 16 + 4 * q + 2];
      const uint4 wD = lw4[cp * 16 + 4 * q + 3];
      const unsigned int wu[16] = {wA.x, wA.y, wA.z, wA.w, wB.x, wB.y, wB.z, wB.w,
                                   wC.x, wC.y, wC.z, wC.w, wD.x, wD.y, wD.z, wD.w};
#pragma unroll
      for (int u = 0; u < 16; ++u) {
        const f16x2 wh = u2h(wu[u]);
        az[0][u >> 1][u & 1] = DOT2(a0, wh, az[0][u >> 1][u & 1]);
        az[1][u >> 1][u & 1] = DOT2(a1, wh, az[1][u >> 1][u & 1]);
      }
    }
  };

  auto epilogue = [&](int kb, f32x2 (&az)[2][8]) {
    // sigmoid in place -> z
    {
      const float ck = cwS[kb], dk = cbS[kb];
      const f32x2 ckv = {ck, ck}, dkv = {dk, dk};
      const f32x2* rs2 = reinterpret_cast<const f32x2*>(&rsumS[o0]);
      const f32x2* lb2 = reinterpret_cast<const f32x2*>(&lbS[o0]);
#pragma unroll
      for (int s = 0; s < 2; ++s)
#pragma unroll
        for (int u = 0; u < 8; ++u) {
          const f32x2 zv = FMA2(ckv, az[s][u], FMA2(dkv, rs2[u], lb2[u]));
          az[s][u][0] = 1.f / (1.f + __expf(-zv[0]));
          az[s][u][1] = 1.f / (1.f + __expf(-zv[1]));
        }
    }
    // z -> f16 pairs for the fdot2 scorer
    unsigned int zh[2][8];
#pragma unroll
    for (int s = 0; s < 2; ++s)
#pragma unroll
      for (int u = 0; u < 8; ++u) zh[s][u] = pk2u(az[s][u][0], az[s][u][1]);
    // scorer: paired-h parity trick, fdot2 on f16 w1
    float sacc = 0.f;
#pragma unroll
    for (int t = 0; t < 5; ++t) {
      const int hA = 2 * t, hB = 2 * t + 1;
      const uint4 wa0 = *reinterpret_cast<const uint4*>(w1HS + hA * 32 + q * 8);
      const uint4 wa1 = *reinterpret_cast<const uint4*>(w1HS + hA * 32 + q * 8 + 4);
      const uint4 wb0 = *reinterpret_cast<const uint4*>(w1HS + hB * 32 + q * 8);
      const uint4 wb1 = *reinterpret_cast<const uint4*>(w1HS + hB * 32 + q * 8 + 4);
      const unsigned int wau[8] = {wa0.x, wa0.y, wa0.z, wa0.w, wa1.x, wa1.y, wa1.z, wa1.w};
      const unsigned int wbu[8] = {wb0.x, wb0.y, wb0.z, wb0.w, wb1.x, wb1.y, wb1.z, wb1.w};
      float pA0 = 0.f, pA1 = 0.f, pB0 = 0.f, pB1 = 0.f;
#pragma unroll
      for (int u = 0; u < 8; ++u) {
        pA0 = DOT2(u2h(zh[0][u]), u2h(wau[u]), pA0);
        pA1 = DOT2(u2h(zh[1][u]), u2h(wau[u]), pA1);
        pB0 = DOT2(u2h(zh[0][u]), u2h(wbu[u]), pB0);
        pB1 = DOT2(u2h(zh[1][u]), u2h(wbu[u]), pB1);
      }
      pA0 += __shfl_xor(pA0, 1, 64); pA0 += __shfl_xor(pA0, 2, 64);
      pA1 += __shfl_xor(pA1, 1, 64); pA1 += __shfl_xor(pA1, 2, 64);
      pB0 += __shfl_xor(pB0, 1, 64); pB0 += __shfl_xor(pB0, 2, 64);
      pB1 += __shfl_xor(pB1, 1, 64); pB1 += __shfl_xor(pB1, 2, 64);
      const int hm = hA + (q & 1);
      const float pSelA = (q >> 1) ? pA1 : pA0;
      const float pSelB = (q >> 1) ? pB1 : pB0;
      const float pm = (q & 1) ? pSelB : pSelA;
      const float ex = __expf(2.f * (pm + b1S[hm]));
      sacc += w2S[hm] * (1.f - 2.f / (ex + 1.f));
    }
    sacc += __shfl_xor(sacc, 1, 64);
    const int gbase = lane & 60;
    float sc[2];
    sc[0] = __shfl(sacc, gbase + 0, 64);
    sc[1] = __shfl(sacc, gbase + 2, 64);
    // online softmax accumulate
#pragma unroll
    for (int s = 0; s < 2; ++s) {
      const float nm = fmaxf(mrun[s], sc[s]);
      const float f = __expf(mrun[s] - nm), e = __expf(sc[s] - nm);
      denom[s] = denom[s] * f + e;
      const f32x2 fv = {f, f}, ev = {e, e};
#pragma unroll
      for (int u = 0; u < 8; ++u) oacc2[s][u] = FMA2(oacc2[s][u], fv, ev * az[s][u]);
      mrun[s] = nm;
    }
  };

  // ---- prologue: stage bands 0 and 1; GEMM(0) hides band 1's latency
  stage_issue(0);
  stage_write(comHS[0]);
  stage_issue(1);
  __syncthreads();                 // buf0 ready (both waves)
  gemm(comHS[0], accz2[0]);
  stage_write(comHS[1]);
  __syncthreads();                 // buf1 ready

  // ---- pipelined band loop (fully unrolled; parity indices compile-time)
#pragma unroll
  for (int kb = 0; kb < NBAND; ++kb) {
    if (kb < NBAND - 2) stage_issue(kb + 2);
    if (kb < NBAND - 1) gemm(comHS[(kb + 1) & 1], accz2[(kb + 1) & 1]);  // LDS-heavy
    epilogue(kb, accz2[kb & 1]);                                          // VALU-heavy
    if (kb < NBAND - 2) stage_write(comHS[kb & 1]);
    if (kb < NBAND - 1) __syncthreads();
  }

  // ---- store (f32x2: row base 62 floats -> 8B aligned)
#pragma unroll
  for (int s = 0; s < 2; ++s) {
    const int r = row0 + 16 * s;
    if (r < NC) {
      const float inv = 1.f / denom[s];
      const f32x2 invv = {inv, inv};
      float* rowp = outp + (size_t)b * (NC * NC) + r * NC + o0;
      const int ne = (q < 3) ? 8 : 7;
#pragma unroll
      for (int e = 0; e < 8; ++e)
        if (e < ne)
          *reinterpret_cast<f32x2*>(rowp + 2 * e) = oacc2[s][e] * invv;
    }
  }
}

// =====================================================================
// Kernel C: Chebyshev GCN (both adjacencies, shared de@gc_w), feature,
// and the 992->62 FC. wnorm == 1 exactly; relu((h+e)/2) no-op on relu'd h,e.
// =====================================================================
__global__ __launch_bounds__(256) void k_cheb_fc(
    const float* __restrict__ de, const float* __restrict__ hidden,
    const float* __restrict__ essential, const float* __restrict__ gc_w,
    const float* __restrict__ gc_b, const float* __restrict__ fc_w,
    const float* __restrict__ fc_b, float* __restrict__ zmat) {
  const int b = blockIdx.x;
  __shared__ float hidS[NC * NC], essS[NC * NC];
  __shared__ float t0S[NC * NOUT], t1S[NC * NOUT];
  __shared__ float featS[NC * NOUT];
  __shared__ float deS[NC * NBAND];
  __shared__ float red2[256];
  const int tid = threadIdx.x;

  for (int t = tid; t < NC * NBAND; t += 256) deS[t] = de[b * NC * NBAND + t];
  for (int t = tid; t < NC * NC; t += 256) {
    hidS[t] = hidden[b * NC * NC + t];
    essS[t] = essential[b * NC * NC + t];
  }
  __syncthreads();
  for (int t = tid; t < NC * NOUT; t += 256) {
    const int i = t / NOUT, f = t % NOUT;
    float a0 = gc_b[f];
    float a1 = 0.f;
#pragma unroll
    for (int qq = 0; qq < NBAND; ++qq) {
      const float d = deS[i * NBAND + qq];
      a0 += d * gc_w[qq * NOUT + f];
      a1 += d * gc_w[(NBAND + qq) * NOUT + f];
    }
    t0S[t] = a0;
    t1S[t] = a1;
  }
  __syncthreads();
  for (int t = tid; t < NC * NOUT; t += 256) {
    const int i = t / NOUT, f = t % NOUT;
    float sh = 0.f, se = 0.f;
    for (int jj = 0; jj < NC; ++jj) {
      const float t1 = t1S[jj * NOUT + f];
      sh += hidS[i * NC + jj] * t1;
      se += essS[i * NC + jj] * t1;
    }
    const float gb1 = gc_b[NOUT + f];
    const float h = fmaxf(t0S[t] + sh + gb1, 0.f);
    const float e = fmaxf(t0S[t] + se + gb1, 0.f);
    featS[t] = 0.5f * (h + e);
  }
  __syncthreads();
  {
    const int n = tid >> 2, qq = tid & 3;
    float p = 0.f;
    if (n < NC) {
      const float* fw = fc_w + n * (NC * NOUT) + qq * 248;
      const float* fs = featS + qq * 248;
      for (int m = 0; m < 248; ++m) p += fs[m] * fw[m];
    }
    red2[tid] = p;
    __syncthreads();
    if (tid < NC) {
      const float z = red2[tid * 4] + red2[tid * 4 + 1] + red2[tid * 4 + 2] + red2[tid * 4 + 3] + fc_b[tid];
      zmat[b * NC + tid] = z;
    }
  }
}

// =====================================================================
// Kernel D1: batch-norm statistics (training-mode batch stats, ddof=0).
// =====================================================================
__global__ __launch_bounds__(256) void k_bnstats(
    const float* __restrict__ zmat, const float* __restrict__ bn_g,
    const float* __restrict__ bn_b, float* __restrict__ bnp) {
  const int n = blockIdx.x;
  __shared__ float rs[256], rq[256];
  const int tid = threadIdx.x;
  float s = 0.f, sq = 0.f;
  for (int r = tid; r < NB; r += 256) {
    const float v = zmat[r * NC + n];
    s += v;
    sq += v * v;
  }
  rs[tid] = s; rq[tid] = sq;
  __syncthreads();
  for (int st = 128; st > 0; st >>= 1) {
    if (tid < st) { rs[tid] += rs[tid + st]; rq[tid] += rq[tid + st]; }
    __syncthreads();
  }
  if (tid == 0) {
    const float mean = rs[0] * (1.f / NB);
    const float var = rq[0] * (1.f / NB) - mean * mean;
    const float sc = bn_g[n] * rsqrtf(var + 1e-5f);
    bnp[2 * n] = sc;
    bnp[2 * n + 1] = bn_b[n] - mean * sc;
  }
}

// =====================================================================
// Kernel D2: apply BN + sigmoid -> output1; 62->2 FC -> output.
// =====================================================================
__global__ __launch_bounds__(64) void k_bn_out(
    const float* __restrict__ zmat, const float* __restrict__ bnp,
    const float* __restrict__ fc4_w, const float* __restrict__ fc4_b,
    float* __restrict__ out) {
  const int b = blockIdx.x;
  const int lane = threadIdx.x;
  float o1 = 0.f;
  if (lane < NC) {
    float z = zmat[b * NC + lane];
    z = z * bnp[2 * lane] + bnp[2 * lane + 1];
    o1 = 1.f / (1.f + __expf(-z));
    out[b * NC + lane] = o1;
  }
  float p0 = (lane < NC) ? o1 * fc4_w[lane] : 0.f;
  float p1 = (lane < NC) ? o1 * fc4_w[NC + lane] : 0.f;
#pragma unroll
  for (int off = 32; off > 0; off >>= 1) {
    p0 += __shfl_down(p0, off, 64);
    p1 += __shfl_down(p1, off, 64);
  }
  if (lane == 0) {
    out[NB * NC + b * 2 + 0] = p0 + fc4_b[0];
    out[NB * NC + b * 2 + 1] = p1 + fc4_b[1];
  }
}

extern "C" void kernel_launch(void* const* d_in, const int* in_sizes, int n_in,
                              void* d_out, int out_size, void* d_ws, size_t ws_size,
                              hipStream_t stream) {
  const float* de      = (const float*)d_in[0];
  const float* pcc     = (const float*)d_in[1];
  const float* Aadj    = (const float*)d_in[2];
  // d_in[3] conv_w, d_in[4] conv_b: dead (gate cancels in trace-normalized SPD)
  const float* hconv_w = (const float*)d_in[5];
  const float* hconv_b = (const float*)d_in[6];
  const float* hlin_w  = (const float*)d_in[7];
  const float* hlin_b  = (const float*)d_in[8];
  const float* econv_w = (const float*)d_in[9];
  const float* econv_b = (const float*)d_in[10];
  const float* elin_w  = (const float*)d_in[11];
  const float* elin_b  = (const float*)d_in[12];
  const float* att_w1  = (const float*)d_in[13];
  const float* att_b1  = (const float*)d_in[14];
  const float* att_w2  = (const float*)d_in[15];
  const float* gc_w    = (const float*)d_in[16];
  const float* gc_b    = (const float*)d_in[17];
  // d_in[18] wpar: wnorm = exp(w)/exp(w) = 1 exactly for 1-element wpar
  const float* fc_w    = (const float*)d_in[19];
  const float* fc_b    = (const float*)d_in[20];
  const float* bn_g    = (const float*)d_in[21];
  const float* bn_b    = (const float*)d_in[22];
  const float* fc4_w   = (const float*)d_in[23];
  const float* fc4_b   = (const float*)d_in[24];

  float* ws        = (float*)d_ws;
  _Float16* comH   = (_Float16*)ws;                      // 5120*4096 halves = 41.9 MB
  float* hidden    = ws + 10485760;                      //  3,936,256 floats
  float* essential = hidden + (size_t)NB * NC * NC;
  float* zmat      = essential + (size_t)NB * NC * NC;   //     63,488
  float* bnp       = zmat + (size_t)NB * NC;             //        128
  unsigned int* lwTHg = (unsigned int*)(bnp + 128);      //      4,096 u32
  unsigned int* w1Hg  = lwTHg + 4096;                    //        320 u32
  float* rsumG     = (float*)(w1Hg + 512);               //        128
  // total ~74 MB of workspace

  k_spd<<<NB * NBAND, 256, 0, stream>>>(pcc, Aadj, hlin_w, elin_w, att_w1,
                                        comH, lwTHg, w1Hg, rsumG);
  k_branch<<<NB * 2, 128, 0, stream>>>(comH, lwTHg, w1Hg, rsumG,
      hconv_w, hconv_b, hlin_b,
      econv_w, econv_b, elin_b,
      att_b1, att_w2, hidden, essential);
  k_cheb_fc<<<NB, 256, 0, stream>>>(de, hidden, essential, gc_w, gc_b, fc_w, fc_b, zmat);
  k_bnstats<<<NC, 256, 0, stream>>>(zmat, bn_g, bn_b, bnp);
  k_bn_out<<<NB, 64, 0, stream>>>(zmat, bnp, fc4_w, fc4_b, (float*)d_out);
}